// Round 1
// baseline (1796.285 us; speedup 1.0000x reference)
//
#include <hip/hip_runtime.h>
#include <stdint.h>

#define D_   10000
#define DP1  10001
#define NPAD 10112       // 79 * 128  (padded vocab rows for GEMM1)
#define H_   1024
#define BL   4096        // B * L
#define KTP  10016       // 313 * 32  (padded K for GEMM2)

typedef float  f32x4  __attribute__((ext_vector_type(4)));
typedef __bf16 bf16x8 __attribute__((ext_vector_type(8)));
typedef unsigned short u16;
typedef u16    u16x8  __attribute__((ext_vector_type(8)));

// ---------- bf16 helpers (round-to-nearest-even) ----------
__device__ __forceinline__ u16 f2bf(float x) {
    union { float f; unsigned u; } v; v.f = x;
    unsigned r = v.u + 0x7FFFu + ((v.u >> 16) & 1u);
    return (u16)(r >> 16);
}
__device__ __forceinline__ float bf2f(u16 b) {
    union { float f; unsigned u; } v; v.u = ((unsigned)b) << 16;
    return v.f;
}

// async global -> LDS, 16B per lane (HW: wave-uniform base + lane*16)
#define GLOAD_LDS16(gsrc, ldst)                                             \
    __builtin_amdgcn_global_load_lds(                                       \
        (__attribute__((address_space(1))) void*)(void*)(gsrc),             \
        (__attribute__((address_space(3))) void*)(void*)(ldst), 16, 0, 0)

// ---------- prep: split fp32 -> bf16 hi + lo ----------
__global__ __launch_bounds__(256)
void split_desc_k(const float* __restrict__ desc, u16* __restrict__ hi, u16* __restrict__ lo) {
    size_t i = (size_t)blockIdx.x * 256 + threadIdx.x;   // exactly BL*H_
    float x = desc[i];
    u16 h = f2bf(x);
    hi[i] = h;
    lo[i] = f2bf(x - bf2f(h));
}

__global__ __launch_bounds__(256)
void split_fv_k(const float* __restrict__ vocab, const float* __restrict__ defe,
                u16* __restrict__ hi, u16* __restrict__ lo) {
    size_t i = (size_t)blockIdx.x * 256 + threadIdx.x;   // exactly NPAD*H_
    int d = (int)(i >> 10);
    int h = (int)(i & 1023);
    float x = 0.f;
    if (d < D_)       x = vocab[i];
    else if (d == D_) x = defe[h];
    u16 hh = f2bf(x);
    hi[i] = hh;
    lo[i] = f2bf(x - bf2f(hh));
}

// ---------- GEMM1: logits = desc @ full_vocab^T, bf16 hi/lo split (3 MFMAs) ----------
// A: [4096][1024] bf16 (hi,lo), B: [NPAD][1024] bf16 (hi,lo), C: [4096][10001] fp32
__global__ __launch_bounds__(256, 2)
void gemm1_k(const u16* __restrict__ Ahg, const u16* __restrict__ Alg,
             const u16* __restrict__ Bhg, const u16* __restrict__ Blg,
             float* __restrict__ C) {
    __shared__ u16 Ah[128 * 32], Al[128 * 32], Bh[128 * 32], Bl[128 * 32];

    const int tid  = threadIdx.x;
    const int wave = tid >> 6, lane = tid & 63;
    const int wr = wave >> 1, wc = wave & 1;
    const int quad = lane >> 4, r16 = lane & 15;
    const int m0 = blockIdx.y * 128, n0 = blockIdx.x * 128;

    f32x4 zero = {0.f, 0.f, 0.f, 0.f};
    f32x4 acc[4][4];
#pragma unroll
    for (int i = 0; i < 4; i++)
#pragma unroll
        for (int j = 0; j < 4; j++) acc[i][j] = zero;

    // staging: per array, 2 instrs/thread; instr r covers rows r*64 + wave*16 + (lane>>2)
    const int srow = wave * 16 + (lane >> 2);
    const int scol = (lane & 3) * 8;
    const u16* a_h = Ahg + (size_t)(m0 + srow) * H_ + scol;
    const u16* a_l = Alg + (size_t)(m0 + srow) * H_ + scol;
    const u16* b_h = Bhg + (size_t)(n0 + srow) * H_ + scol;
    const u16* b_l = Blg + (size_t)(n0 + srow) * H_ + scol;
    const int ldsoff = wave * 1024 + lane * 16;   // bytes
    char* lAh = (char*)Ah + ldsoff;
    char* lAl = (char*)Al + ldsoff;
    char* lBh = (char*)Bh + ldsoff;
    char* lBl = (char*)Bl + ldsoff;

    for (int k0 = 0; k0 < H_; k0 += 32) {
        __syncthreads();
#pragma unroll
        for (int r = 0; r < 2; r++) {
            size_t go = (size_t)r * 64 * H_ + k0;
            GLOAD_LDS16(a_h + go, lAh + r * 4096);
            GLOAD_LDS16(a_l + go, lAl + r * 4096);
            GLOAD_LDS16(b_h + go, lBh + r * 4096);
            GLOAD_LDS16(b_l + go, lBl + r * 4096);
        }
        __syncthreads();

        bf16x8 afh[4], afl[4], bfh[4], bfl[4];
#pragma unroll
        for (int i = 0; i < 4; i++) {
            int ar = (wr * 64 + i * 16 + r16) * 32 + quad * 8;
            int br = (wc * 64 + i * 16 + r16) * 32 + quad * 8;
            afh[i] = *(const bf16x8*)&Ah[ar];
            afl[i] = *(const bf16x8*)&Al[ar];
            bfh[i] = *(const bf16x8*)&Bh[br];
            bfl[i] = *(const bf16x8*)&Bl[br];
        }
#pragma unroll
        for (int i = 0; i < 4; i++)
#pragma unroll
            for (int j = 0; j < 4; j++) {
                acc[i][j] = __builtin_amdgcn_mfma_f32_16x16x32_bf16(afh[i], bfh[j], acc[i][j], 0, 0, 0);
                acc[i][j] = __builtin_amdgcn_mfma_f32_16x16x32_bf16(afh[i], bfl[j], acc[i][j], 0, 0, 0);
                acc[i][j] = __builtin_amdgcn_mfma_f32_16x16x32_bf16(afl[i], bfh[j], acc[i][j], 0, 0, 0);
            }
    }

    // C/D layout: row = quad*4 + reg, col = lane&15
#pragma unroll
    for (int i = 0; i < 4; i++) {
        int gm = m0 + wr * 64 + i * 16 + quad * 4;
#pragma unroll
        for (int j = 0; j < 4; j++) {
            int gn = n0 + wc * 64 + j * 16 + r16;
            if (gn < DP1) {
#pragma unroll
                for (int reg = 0; reg < 4; reg++)
                    C[(size_t)(gm + reg) * DP1 + gn] = acc[i][j][reg];
            }
        }
    }
}

// ---------- softmax over DP1, one block per row, in-place ----------
__global__ __launch_bounds__(256)
void softmax_k(float* __restrict__ sim) {
    __shared__ float buf[DP1];
    __shared__ float red[8];
    const int tid = threadIdx.x;
    float* rowp = sim + (size_t)blockIdx.x * DP1;

    float mx = -3.4e38f;
    for (int i = tid; i < DP1; i += 256) { float v = rowp[i]; buf[i] = v; mx = fmaxf(mx, v); }
#pragma unroll
    for (int off = 32; off; off >>= 1) mx = fmaxf(mx, __shfl_down(mx, off, 64));
    if ((tid & 63) == 0) red[tid >> 6] = mx;
    __syncthreads();
    if (tid == 0) red[0] = fmaxf(fmaxf(red[0], red[1]), fmaxf(red[2], red[3]));
    __syncthreads();
    mx = red[0];
    __syncthreads();

    float s = 0.f;
    for (int i = tid; i < DP1; i += 256) { float e = __expf(buf[i] - mx); buf[i] = e; s += e; }
#pragma unroll
    for (int off = 32; off; off >>= 1) s += __shfl_down(s, off, 64);
    if ((tid & 63) == 0) red[tid >> 6] = s;
    __syncthreads();
    if (tid == 0) red[0] = red[0] + red[1] + red[2] + red[3];
    __syncthreads();
    float inv = 1.f / red[0];
    for (int i = tid; i < DP1; i += 256) rowp[i] = buf[i] * inv;
}

// ---------- transpose vocab fp32 [D_][H_] -> vocab_t bf16 [H_][KTP] (pad cols = 0) ----------
__global__ __launch_bounds__(256)
void transpose_k(const float* __restrict__ vocab, u16* __restrict__ vt) {
    __shared__ u16 t[32][33];
    int d0 = blockIdx.x * 32, h0 = blockIdx.y * 32;
    int c = threadIdx.x & 31, r = threadIdx.x >> 5;   // r in 0..7
#pragma unroll
    for (int rr = 0; rr < 32; rr += 8) {
        int d = d0 + r + rr;
        float x = (d < D_) ? vocab[(size_t)d * H_ + h0 + c] : 0.f;
        t[r + rr][c] = f2bf(x);
    }
    __syncthreads();
#pragma unroll
    for (int rr = 0; rr < 32; rr += 8) {
        int h = h0 + r + rr;
        vt[(size_t)h * KTP + d0 + c] = t[c][r + rr];
    }
}

// ---------- GEMM2: concept = sim[:, :D_] @ vocab + sim[:,D_]*desc ----------
// A: sim fp32 [4096][DP1] converted on the fly; B: vocab_t bf16 [H_][KTP]
__global__ __launch_bounds__(256, 2)
void gemm2_k(const float* __restrict__ sim, const u16* __restrict__ vt,
             const float* __restrict__ desc, float* __restrict__ out) {
    __shared__ u16 As[128 * 32];   // 8 KB
    __shared__ u16 Bs[64 * 32];    // 4 KB

    const int tid  = threadIdx.x;
    const int wave = tid >> 6, lane = tid & 63;
    const int wr = wave >> 1, wc = wave & 1;
    const int quad = lane >> 4, r16 = lane & 15;
    const int m0 = blockIdx.y * 128, n0 = blockIdx.x * 64;

    f32x4 zero = {0.f, 0.f, 0.f, 0.f};
    f32x4 acc[4][2];
#pragma unroll
    for (int i = 0; i < 4; i++) { acc[i][0] = zero; acc[i][1] = zero; }

    const int arow = tid >> 1;
    const int ak0  = (tid & 1) * 16;
    const float* arp = sim + (size_t)(m0 + arow) * DP1;
    const u16* bsrc = vt + (size_t)(n0 + wave * 16 + (lane >> 2)) * KTP + (lane & 3) * 8;
    char* lB = (char*)Bs + wave * 1024 + lane * 16;

    for (int k0 = 0; k0 < KTP; k0 += 32) {
        __syncthreads();
        GLOAD_LDS16(bsrc + k0, lB);
        u16 tmp[16];
#pragma unroll
        for (int t = 0; t < 16; t++) {
            int k = k0 + ak0 + t;
            float v = (k < D_) ? arp[k] : 0.f;
            tmp[t] = f2bf(v);
        }
        u16x8 v0, v1;
#pragma unroll
        for (int t = 0; t < 8; t++) { v0[t] = tmp[t]; v1[t] = tmp[8 + t]; }
        *(u16x8*)&As[arow * 32 + ak0]     = v0;
        *(u16x8*)&As[arow * 32 + ak0 + 8] = v1;
        __syncthreads();

        bf16x8 af[4], bf[2];
#pragma unroll
        for (int i = 0; i < 4; i++)
            af[i] = *(const bf16x8*)&As[(wr * 64 + i * 16 + r16) * 32 + quad * 8];
#pragma unroll
        for (int j = 0; j < 2; j++)
            bf[j] = *(const bf16x8*)&Bs[(wc * 32 + j * 16 + r16) * 32 + quad * 8];
#pragma unroll
        for (int i = 0; i < 4; i++)
#pragma unroll
            for (int j = 0; j < 2; j++)
                acc[i][j] = __builtin_amdgcn_mfma_f32_16x16x32_bf16(af[i], bf[j], acc[i][j], 0, 0, 0);
    }

#pragma unroll
    for (int i = 0; i < 4; i++) {
        int gm0 = m0 + wr * 64 + i * 16 + quad * 4;
#pragma unroll
        for (int j = 0; j < 2; j++) {
            int gn = n0 + wc * 32 + j * 16 + r16;
#pragma unroll
            for (int reg = 0; reg < 4; reg++) {
                int m = gm0 + reg;
                float w = sim[(size_t)m * DP1 + D_];
                out[(size_t)m * H_ + gn] = acc[i][j][reg] + w * desc[(size_t)m * H_ + gn];
            }
        }
    }
}

// ---------- fallback (ws too small): exact fp32, slow but correct ----------
__global__ __launch_bounds__(256)
void naive_logits_k(const float* __restrict__ vocab, const float* __restrict__ desc,
                    const float* __restrict__ defe, float* __restrict__ sim) {
    int d = blockIdx.x * 256 + threadIdx.x;
    if (d >= DP1) return;
    const float* vr = (d < D_) ? (vocab + (size_t)d * H_) : defe;
    const float* dr = desc + (size_t)blockIdx.y * H_;
    float s = 0.f;
    for (int h = 0; h < H_; h++) s = fmaf(dr[h], vr[h], s);
    sim[(size_t)blockIdx.y * DP1 + d] = s;
}

__global__ __launch_bounds__(256)
void naive_out_k(const float* __restrict__ vocab, const float* __restrict__ desc,
                 const float* __restrict__ sim, float* __restrict__ out) {
    int h = blockIdx.x * 256 + threadIdx.x;
    int bl = blockIdx.y;
    const float* sr = sim + (size_t)bl * DP1;
    float s = 0.f;
    for (int d = 0; d < D_; d++) s = fmaf(sr[d], vocab[(size_t)d * H_ + h], s);
    s += sr[D_] * desc[(size_t)bl * H_ + h];
    out[(size_t)bl * H_ + h] = s;
}

extern "C" void kernel_launch(void* const* d_in, const int* in_sizes, int n_in,
                              void* d_out, int out_size, void* d_ws, size_t ws_size,
                              hipStream_t stream) {
    (void)in_sizes; (void)n_in; (void)out_size;
    const float* vocab = (const float*)d_in[0];
    const float* desc  = (const float*)d_in[1];
    const float* defe  = (const float*)d_in[2];
    float* out = (float*)d_out;                          // concept: [4096][1024]
    float* sim = out + (size_t)BL * H_;                  // sim:     [4096][10001]

    // ws layout (bytes):
    //   desc_hi @ 0          (8,388,608)
    //   desc_lo @ 8,388,608  (8,388,608)
    //   fv_hi   @ 16,777,216 (20,709,376 = NPAD*H_*2)
    //   fv_lo   @ 37,486,592 (20,709,376)         -> REQ = 58,195,968
    //   vocab_t @ 0          (20,512,768 = H_*KTP*2) overlaps regions dead after gemm1
    const size_t REQ = 58195968ull;
    if (ws_size >= REQ) {
        char* ws = (char*)d_ws;
        u16* dhi = (u16*)(ws + 0);
        u16* dlo = (u16*)(ws + 8388608);
        u16* fhi = (u16*)(ws + 16777216);
        u16* flo = (u16*)(ws + 37486592);
        u16* vt  = (u16*)(ws + 0);

        split_desc_k<<<16384, 256, 0, stream>>>(desc, dhi, dlo);
        split_fv_k<<<40448, 256, 0, stream>>>(vocab, defe, fhi, flo);
        gemm1_k<<<dim3(79, 32), 256, 0, stream>>>(dhi, dlo, fhi, flo, sim);
        softmax_k<<<4096, 256, 0, stream>>>(sim);
        transpose_k<<<dim3(313, 32), 256, 0, stream>>>(vocab, vt);   // after gemm1 (overlap)
        gemm2_k<<<dim3(16, 32), 256, 0, stream>>>(sim, vt, desc, out);
    } else {
        naive_logits_k<<<dim3(40, BL), 256, 0, stream>>>(vocab, desc, defe, sim);
        softmax_k<<<4096, 256, 0, stream>>>(sim);
        naive_out_k<<<dim3(4, BL), 256, 0, stream>>>(vocab, desc, sim, out);
    }
}

// Round 2
// 938.081 us; speedup vs baseline: 1.9148x; 1.9148x over previous
//
#include <hip/hip_runtime.h>
#include <stdint.h>

#define D_   10000
#define DP1  10001
#define NPAD 10112       // 79 * 128  (padded vocab rows for GEMM1)
#define H_   1024
#define BL   4096        // B * L
#define KTP  10016       // 313 * 32  (padded K for GEMM2)

typedef float  f32x4  __attribute__((ext_vector_type(4)));
typedef __bf16 bf16x8 __attribute__((ext_vector_type(8)));
typedef unsigned short u16;
typedef u16    u16x8  __attribute__((ext_vector_type(8)));

// ---------- bf16 helpers (round-to-nearest-even) ----------
__device__ __forceinline__ u16 f2bf(float x) {
    union { float f; unsigned u; } v; v.f = x;
    unsigned r = v.u + 0x7FFFu + ((v.u >> 16) & 1u);
    return (u16)(r >> 16);
}
__device__ __forceinline__ float bf2f(u16 b) {
    union { float f; unsigned u; } v; v.u = ((unsigned)b) << 16;
    return v.f;
}

// async global -> LDS, 16B per lane (HW: wave-uniform base + lane*16)
#define GLOAD_LDS16(gsrc, ldst)                                             \
    __builtin_amdgcn_global_load_lds(                                       \
        (__attribute__((address_space(1))) void*)(void*)(gsrc),             \
        (__attribute__((address_space(3))) void*)(void*)(ldst), 16, 0, 0)

// ---------- prep: split fp32 -> bf16 hi + lo ----------
__global__ __launch_bounds__(256)
void split_desc_k(const float* __restrict__ desc, u16* __restrict__ hi, u16* __restrict__ lo) {
    size_t i = (size_t)blockIdx.x * 256 + threadIdx.x;   // exactly BL*H_
    float x = desc[i];
    u16 h = f2bf(x);
    hi[i] = h;
    lo[i] = f2bf(x - bf2f(h));
}

__global__ __launch_bounds__(256)
void split_fv_k(const float* __restrict__ vocab, const float* __restrict__ defe,
                u16* __restrict__ hi, u16* __restrict__ lo) {
    size_t i = (size_t)blockIdx.x * 256 + threadIdx.x;   // exactly NPAD*H_
    int d = (int)(i >> 10);
    int h = (int)(i & 1023);
    float x = 0.f;
    if (d < D_)       x = vocab[i];
    else if (d == D_) x = defe[h];
    u16 hh = f2bf(x);
    hi[i] = hh;
    lo[i] = f2bf(x - bf2f(hh));
}

// ---------- GEMM1: logits = desc @ full_vocab^T, bf16 hi/lo split (3 MFMAs) ----------
// A: [4096][1024] bf16 (hi,lo), B: [NPAD][1024] bf16 (hi,lo), C: [4096][10001] fp32
__global__ __launch_bounds__(256, 2)
void gemm1_k(const u16* __restrict__ Ahg, const u16* __restrict__ Alg,
             const u16* __restrict__ Bhg, const u16* __restrict__ Blg,
             float* __restrict__ C) {
    __shared__ u16 Ah[128 * 32], Al[128 * 32], Bh[128 * 32], Bl[128 * 32];

    const int tid  = threadIdx.x;
    const int wave = tid >> 6, lane = tid & 63;
    const int wr = wave >> 1, wc = wave & 1;
    const int quad = lane >> 4, r16 = lane & 15;
    const int m0 = blockIdx.y * 128, n0 = blockIdx.x * 128;

    f32x4 zero = {0.f, 0.f, 0.f, 0.f};
    f32x4 acc[4][4];
#pragma unroll
    for (int i = 0; i < 4; i++)
#pragma unroll
        for (int j = 0; j < 4; j++) acc[i][j] = zero;

    const int srow = wave * 16 + (lane >> 2);
    const int scol = (lane & 3) * 8;
    const u16* a_h = Ahg + (size_t)(m0 + srow) * H_ + scol;
    const u16* a_l = Alg + (size_t)(m0 + srow) * H_ + scol;
    const u16* b_h = Bhg + (size_t)(n0 + srow) * H_ + scol;
    const u16* b_l = Blg + (size_t)(n0 + srow) * H_ + scol;
    const int ldsoff = wave * 1024 + lane * 16;   // bytes
    char* lAh = (char*)Ah + ldsoff;
    char* lAl = (char*)Al + ldsoff;
    char* lBh = (char*)Bh + ldsoff;
    char* lBl = (char*)Bl + ldsoff;

    for (int k0 = 0; k0 < H_; k0 += 32) {
        __syncthreads();
#pragma unroll
        for (int r = 0; r < 2; r++) {
            size_t go = (size_t)r * 64 * H_ + k0;
            GLOAD_LDS16(a_h + go, lAh + r * 4096);
            GLOAD_LDS16(a_l + go, lAl + r * 4096);
            GLOAD_LDS16(b_h + go, lBh + r * 4096);
            GLOAD_LDS16(b_l + go, lBl + r * 4096);
        }
        __syncthreads();

        bf16x8 afh[4], afl[4], bfh[4], bfl[4];
#pragma unroll
        for (int i = 0; i < 4; i++) {
            int ar = (wr * 64 + i * 16 + r16) * 32 + quad * 8;
            int br = (wc * 64 + i * 16 + r16) * 32 + quad * 8;
            afh[i] = *(const bf16x8*)&Ah[ar];
            afl[i] = *(const bf16x8*)&Al[ar];
            bfh[i] = *(const bf16x8*)&Bh[br];
            bfl[i] = *(const bf16x8*)&Bl[br];
        }
#pragma unroll
        for (int i = 0; i < 4; i++)
#pragma unroll
            for (int j = 0; j < 4; j++) {
                acc[i][j] = __builtin_amdgcn_mfma_f32_16x16x32_bf16(afh[i], bfh[j], acc[i][j], 0, 0, 0);
                acc[i][j] = __builtin_amdgcn_mfma_f32_16x16x32_bf16(afh[i], bfl[j], acc[i][j], 0, 0, 0);
                acc[i][j] = __builtin_amdgcn_mfma_f32_16x16x32_bf16(afl[i], bfh[j], acc[i][j], 0, 0, 0);
            }
    }

    // C/D layout: row = quad*4 + reg, col = lane&15
#pragma unroll
    for (int i = 0; i < 4; i++) {
        int gm = m0 + wr * 64 + i * 16 + quad * 4;
#pragma unroll
        for (int j = 0; j < 4; j++) {
            int gn = n0 + wc * 64 + j * 16 + r16;
            if (gn < DP1) {
#pragma unroll
                for (int reg = 0; reg < 4; reg++)
                    C[(size_t)(gm + reg) * DP1 + gn] = acc[i][j][reg];
            }
        }
    }
}

// ---------- softmax over DP1, one block per row, in-place; optional bf16 emit ----------
__global__ __launch_bounds__(256)
void softmax_k(float* __restrict__ sim, u16* __restrict__ simb) {
    __shared__ float buf[DP1];
    __shared__ float red[8];
    const int tid = threadIdx.x;
    const int row = blockIdx.x;
    float* rowp = sim + (size_t)row * DP1;

    float mx = -3.4e38f;
    for (int i = tid; i < DP1; i += 256) { float v = rowp[i]; buf[i] = v; mx = fmaxf(mx, v); }
#pragma unroll
    for (int off = 32; off; off >>= 1) mx = fmaxf(mx, __shfl_down(mx, off, 64));
    if ((tid & 63) == 0) red[tid >> 6] = mx;
    __syncthreads();
    if (tid == 0) red[0] = fmaxf(fmaxf(red[0], red[1]), fmaxf(red[2], red[3]));
    __syncthreads();
    mx = red[0];
    __syncthreads();

    float s = 0.f;
    for (int i = tid; i < DP1; i += 256) { float e = __expf(buf[i] - mx); buf[i] = e; s += e; }
#pragma unroll
    for (int off = 32; off; off >>= 1) s += __shfl_down(s, off, 64);
    if ((tid & 63) == 0) red[tid >> 6] = s;
    __syncthreads();
    if (tid == 0) red[0] = red[0] + red[1] + red[2] + red[3];
    __syncthreads();
    float inv = 1.f / red[0];
    if (simb) {
        u16* sbp = simb + (size_t)row * KTP;
        for (int i = tid; i < DP1; i += 256) {
            float p = buf[i] * inv;
            rowp[i] = p;
            // concept columns only; default slot (i==D_) is handled in the epilogue
            sbp[i] = (i < D_) ? f2bf(p) : (u16)0;
        }
        // zero K-padding cols D_+1 .. KTP-1 (15 cols)
        for (int i = DP1 + tid; i < KTP; i += 256) sbp[i] = 0;
    } else {
        for (int i = tid; i < DP1; i += 256) rowp[i] = buf[i] * inv;
    }
}

// ---------- transpose vocab fp32 [D_][H_] -> vocab_t bf16 [H_][KTP] (pad cols = 0) ----------
__global__ __launch_bounds__(256)
void transpose_k(const float* __restrict__ vocab, u16* __restrict__ vt) {
    __shared__ u16 t[32][33];
    int d0 = blockIdx.x * 32, h0 = blockIdx.y * 32;
    int c = threadIdx.x & 31, r = threadIdx.x >> 5;   // r in 0..7
#pragma unroll
    for (int rr = 0; rr < 32; rr += 8) {
        int d = d0 + r + rr;
        float x = (d < D_) ? vocab[(size_t)d * H_ + h0 + c] : 0.f;
        t[r + rr][c] = f2bf(x);
    }
    __syncthreads();
#pragma unroll
    for (int rr = 0; rr < 32; rr += 8) {
        int h = h0 + r + rr;
        vt[(size_t)h * KTP + d0 + c] = t[c][r + rr];
    }
}

// ---------- GEMM2 (fast): concept = simb @ vocab_t^T + sim[:,D_]*desc ----------
// A: simb bf16 [4096][KTP]; B: vocab_t bf16 [H_][KTP]; C: out fp32 [4096][1024]
// Same m97-style structure as gemm1: 128x128 tile, BK=32, global_load_lds w=16.
__global__ __launch_bounds__(256, 2)
void gemm2_big_k(const u16* __restrict__ simb, const u16* __restrict__ vt,
                 const float* __restrict__ sim, const float* __restrict__ desc,
                 float* __restrict__ out) {
    __shared__ u16 As[128 * 32], Bs[128 * 32];

    const int tid  = threadIdx.x;
    const int wave = tid >> 6, lane = tid & 63;
    const int wr = wave >> 1, wc = wave & 1;
    const int quad = lane >> 4, r16 = lane & 15;
    const int m0 = blockIdx.y * 128, n0 = blockIdx.x * 128;

    f32x4 zero = {0.f, 0.f, 0.f, 0.f};
    f32x4 acc[4][4];
#pragma unroll
    for (int i = 0; i < 4; i++)
#pragma unroll
        for (int j = 0; j < 4; j++) acc[i][j] = zero;

    const int srow = wave * 16 + (lane >> 2);
    const int scol = (lane & 3) * 8;
    const u16* a_s = simb + (size_t)(m0 + srow) * KTP + scol;
    const u16* b_s = vt   + (size_t)(n0 + srow) * KTP + scol;
    const int ldsoff = wave * 1024 + lane * 16;   // bytes
    char* lA = (char*)As + ldsoff;
    char* lB = (char*)Bs + ldsoff;

    for (int k0 = 0; k0 < KTP; k0 += 32) {
        __syncthreads();
#pragma unroll
        for (int r = 0; r < 2; r++) {
            size_t go = (size_t)r * 64 * KTP + k0;
            GLOAD_LDS16(a_s + go, lA + r * 4096);
            GLOAD_LDS16(b_s + go, lB + r * 4096);
        }
        __syncthreads();

        bf16x8 af[4], bf[4];
#pragma unroll
        for (int i = 0; i < 4; i++) {
            af[i] = *(const bf16x8*)&As[(wr * 64 + i * 16 + r16) * 32 + quad * 8];
            bf[i] = *(const bf16x8*)&Bs[(wc * 64 + i * 16 + r16) * 32 + quad * 8];
        }
#pragma unroll
        for (int i = 0; i < 4; i++)
#pragma unroll
            for (int j = 0; j < 4; j++)
                acc[i][j] = __builtin_amdgcn_mfma_f32_16x16x32_bf16(af[i], bf[j], acc[i][j], 0, 0, 0);
    }

#pragma unroll
    for (int i = 0; i < 4; i++) {
        int gm0 = m0 + wr * 64 + i * 16 + quad * 4;
#pragma unroll
        for (int reg = 0; reg < 4; reg++) {
            int m = gm0 + reg;
            float w = sim[(size_t)m * DP1 + D_];
#pragma unroll
            for (int j = 0; j < 4; j++) {
                int gn = n0 + wc * 64 + j * 16 + r16;
                out[(size_t)m * H_ + gn] = acc[i][j][reg] + w * desc[(size_t)m * H_ + gn];
            }
        }
    }
}

// ---------- GEMM2 (medium path, kept as fallback) ----------
__global__ __launch_bounds__(256, 2)
void gemm2_k(const float* __restrict__ sim, const u16* __restrict__ vt,
             const float* __restrict__ desc, float* __restrict__ out) {
    __shared__ u16 As[128 * 32];
    __shared__ u16 Bs[64 * 32];

    const int tid  = threadIdx.x;
    const int wave = tid >> 6, lane = tid & 63;
    const int wr = wave >> 1, wc = wave & 1;
    const int quad = lane >> 4, r16 = lane & 15;
    const int m0 = blockIdx.y * 128, n0 = blockIdx.x * 64;

    f32x4 zero = {0.f, 0.f, 0.f, 0.f};
    f32x4 acc[4][2];
#pragma unroll
    for (int i = 0; i < 4; i++) { acc[i][0] = zero; acc[i][1] = zero; }

    const int arow = tid >> 1;
    const int ak0  = (tid & 1) * 16;
    const float* arp = sim + (size_t)(m0 + arow) * DP1;
    const u16* bsrc = vt + (size_t)(n0 + wave * 16 + (lane >> 2)) * KTP + (lane & 3) * 8;
    char* lB = (char*)Bs + wave * 1024 + lane * 16;

    for (int k0 = 0; k0 < KTP; k0 += 32) {
        __syncthreads();
        GLOAD_LDS16(bsrc + k0, lB);
        u16 tmp[16];
#pragma unroll
        for (int t = 0; t < 16; t++) {
            int k = k0 + ak0 + t;
            float v = (k < D_) ? arp[k] : 0.f;
            tmp[t] = f2bf(v);
        }
        u16x8 v0, v1;
#pragma unroll
        for (int t = 0; t < 8; t++) { v0[t] = tmp[t]; v1[t] = tmp[8 + t]; }
        *(u16x8*)&As[arow * 32 + ak0]     = v0;
        *(u16x8*)&As[arow * 32 + ak0 + 8] = v1;
        __syncthreads();

        bf16x8 af[4], bf[2];
#pragma unroll
        for (int i = 0; i < 4; i++)
            af[i] = *(const bf16x8*)&As[(wr * 64 + i * 16 + r16) * 32 + quad * 8];
#pragma unroll
        for (int j = 0; j < 2; j++)
            bf[j] = *(const bf16x8*)&Bs[(wc * 32 + j * 16 + r16) * 32 + quad * 8];
#pragma unroll
        for (int i = 0; i < 4; i++)
#pragma unroll
            for (int j = 0; j < 2; j++)
                acc[i][j] = __builtin_amdgcn_mfma_f32_16x16x32_bf16(af[i], bf[j], acc[i][j], 0, 0, 0);
    }

#pragma unroll
    for (int i = 0; i < 4; i++) {
        int gm0 = m0 + wr * 64 + i * 16 + quad * 4;
#pragma unroll
        for (int j = 0; j < 2; j++) {
            int gn = n0 + wc * 32 + j * 16 + r16;
#pragma unroll
            for (int reg = 0; reg < 4; reg++) {
                int m = gm0 + reg;
                float w = sim[(size_t)m * DP1 + D_];
                out[(size_t)m * H_ + gn] = acc[i][j][reg] + w * desc[(size_t)m * H_ + gn];
            }
        }
    }
}

// ---------- fallback (ws too small): exact fp32, slow but correct ----------
__global__ __launch_bounds__(256)
void naive_logits_k(const float* __restrict__ vocab, const float* __restrict__ desc,
                    const float* __restrict__ defe, float* __restrict__ sim) {
    int d = blockIdx.x * 256 + threadIdx.x;
    if (d >= DP1) return;
    const float* vr = (d < D_) ? (vocab + (size_t)d * H_) : defe;
    const float* dr = desc + (size_t)blockIdx.y * H_;
    float s = 0.f;
    for (int h = 0; h < H_; h++) s = fmaf(dr[h], vr[h], s);
    sim[(size_t)blockIdx.y * DP1 + d] = s;
}

__global__ __launch_bounds__(256)
void naive_out_k(const float* __restrict__ vocab, const float* __restrict__ desc,
                 const float* __restrict__ sim, float* __restrict__ out) {
    int h = blockIdx.x * 256 + threadIdx.x;
    int bl = blockIdx.y;
    const float* sr = sim + (size_t)bl * DP1;
    float s = 0.f;
    for (int d = 0; d < D_; d++) s = fmaf(sr[d], vocab[(size_t)d * H_ + h], s);
    s += sr[D_] * desc[(size_t)bl * H_ + h];
    out[(size_t)bl * H_ + h] = s;
}

extern "C" void kernel_launch(void* const* d_in, const int* in_sizes, int n_in,
                              void* d_out, int out_size, void* d_ws, size_t ws_size,
                              hipStream_t stream) {
    (void)in_sizes; (void)n_in; (void)out_size;
    const float* vocab = (const float*)d_in[0];
    const float* desc  = (const float*)d_in[1];
    const float* defe  = (const float*)d_in[2];
    float* out = (float*)d_out;                          // concept: [4096][1024]
    float* sim = out + (size_t)BL * H_;                  // sim:     [4096][10001]

    // Phase-1 ws layout (bytes):
    //   desc_hi @ 0          (8,388,608)
    //   desc_lo @ 8,388,608  (8,388,608)
    //   fv_hi   @ 16,777,216 (20,709,376 = NPAD*H_*2)
    //   fv_lo   @ 37,486,592 (20,709,376)          -> REQ1 = 58,195,968
    // Phase-2 (after gemm1, phase-1 arrays dead):
    //   vocab_t @ 0          (20,512,768 = H_*KTP*2)
    //   simb    @ 20,512,768 (82,051,072 = BL*KTP*2) -> REQ2 = 102,563,840
    const size_t REQ1 = 58195968ull;
    const size_t REQ2 = 102563840ull;
    char* ws = (char*)d_ws;

    if (ws_size >= REQ2) {
        u16* dhi  = (u16*)(ws + 0);
        u16* dlo  = (u16*)(ws + 8388608);
        u16* fhi  = (u16*)(ws + 16777216);
        u16* flo  = (u16*)(ws + 37486592);
        u16* vt   = (u16*)(ws + 0);
        u16* simb = (u16*)(ws + 20512768);

        split_desc_k<<<16384, 256, 0, stream>>>(desc, dhi, dlo);
        split_fv_k<<<40448, 256, 0, stream>>>(vocab, defe, fhi, flo);
        gemm1_k<<<dim3(79, 32), 256, 0, stream>>>(dhi, dlo, fhi, flo, sim);
        softmax_k<<<4096, 256, 0, stream>>>(sim, simb);
        transpose_k<<<dim3(313, 32), 256, 0, stream>>>(vocab, vt);
        gemm2_big_k<<<dim3(8, 32), 256, 0, stream>>>(simb, vt, sim, desc, out);
    } else if (ws_size >= REQ1) {
        u16* dhi = (u16*)(ws + 0);
        u16* dlo = (u16*)(ws + 8388608);
        u16* fhi = (u16*)(ws + 16777216);
        u16* flo = (u16*)(ws + 37486592);
        u16* vt  = (u16*)(ws + 0);

        split_desc_k<<<16384, 256, 0, stream>>>(desc, dhi, dlo);
        split_fv_k<<<40448, 256, 0, stream>>>(vocab, defe, fhi, flo);
        gemm1_k<<<dim3(79, 32), 256, 0, stream>>>(dhi, dlo, fhi, flo, sim);
        softmax_k<<<4096, 256, 0, stream>>>(sim, (u16*)nullptr);
        transpose_k<<<dim3(313, 32), 256, 0, stream>>>(vocab, vt);
        gemm2_k<<<dim3(16, 32), 256, 0, stream>>>(sim, vt, desc, out);
    } else {
        naive_logits_k<<<dim3(40, BL), 256, 0, stream>>>(vocab, desc, defe, sim);
        softmax_k<<<4096, 256, 0, stream>>>(sim, (u16*)nullptr);
        naive_out_k<<<dim3(4, BL), 256, 0, stream>>>(vocab, desc, sim, out);
    }
}

// Round 3
// 823.173 us; speedup vs baseline: 2.1821x; 1.1396x over previous
//
#include <hip/hip_runtime.h>
#include <stdint.h>

#define D_   10000
#define DP1  10001
#define NPAD 10112       // 79 * 128  (padded vocab rows for GEMM1)
#define H_   1024
#define BL   4096        // B * L
#define KTP  10016       // 313 * 32  (padded K for GEMM2)
#define KCH  2528        // split-K chunk (79 K-steps); 4 chunks cover KTP

typedef float  f32x4  __attribute__((ext_vector_type(4)));
typedef __bf16 bf16x8 __attribute__((ext_vector_type(8)));
typedef unsigned short u16;
typedef u16    u16x8  __attribute__((ext_vector_type(8)));

// ---------- bf16 helpers (round-to-nearest-even) ----------
__device__ __forceinline__ u16 f2bf(float x) {
    union { float f; unsigned u; } v; v.f = x;
    unsigned r = v.u + 0x7FFFu + ((v.u >> 16) & 1u);
    return (u16)(r >> 16);
}
__device__ __forceinline__ float bf2f(u16 b) {
    union { float f; unsigned u; } v; v.u = ((unsigned)b) << 16;
    return v.f;
}

// async global -> LDS, 16B per lane (HW: wave-uniform base + lane*16)
#define GLOAD_LDS16(gsrc, ldst)                                             \
    __builtin_amdgcn_global_load_lds(                                       \
        (__attribute__((address_space(1))) void*)(void*)(gsrc),             \
        (__attribute__((address_space(3))) void*)(void*)(ldst), 16, 0, 0)

// LDS chunk swizzle: physical 16B-chunk p at row r holds logical chunk p ^ ((r>>1)&3).
// Staging permutes the GLOBAL source per lane (LDS dest must stay base+lane*16);
// fragment reads XOR the quad index. Bank math: groups (4r + (q^((r>>1)&3))) % 8
// hit all 8 16B-groups across r -> 2-way aliasing only (free per m136).

// ---------- prep: split fp32 -> bf16 hi + lo ----------
__global__ __launch_bounds__(256)
void split_desc_k(const float* __restrict__ desc, u16* __restrict__ hi, u16* __restrict__ lo) {
    size_t i = (size_t)blockIdx.x * 256 + threadIdx.x;   // exactly BL*H_
    float x = desc[i];
    u16 h = f2bf(x);
    hi[i] = h;
    lo[i] = f2bf(x - bf2f(h));
}

__global__ __launch_bounds__(256)
void split_fv_k(const float* __restrict__ vocab, const float* __restrict__ defe,
                u16* __restrict__ hi, u16* __restrict__ lo) {
    size_t i = (size_t)blockIdx.x * 256 + threadIdx.x;   // exactly NPAD*H_
    int d = (int)(i >> 10);
    int h = (int)(i & 1023);
    float x = 0.f;
    if (d < D_)       x = vocab[i];
    else if (d == D_) x = defe[h];
    u16 hh = f2bf(x);
    hi[i] = hh;
    lo[i] = f2bf(x - bf2f(hh));
}

// ---------- GEMM1: logits = desc @ full_vocab^T, bf16 hi/lo split (3 MFMAs) ----------
__global__ __launch_bounds__(256, 2)
void gemm1_k(const u16* __restrict__ Ahg, const u16* __restrict__ Alg,
             const u16* __restrict__ Bhg, const u16* __restrict__ Blg,
             float* __restrict__ C) {
    __shared__ u16 Ah[128 * 32], Al[128 * 32], Bh[128 * 32], Bl[128 * 32];

    const int tid  = threadIdx.x;
    const int wave = tid >> 6, lane = tid & 63;
    const int wr = wave >> 1, wc = wave & 1;
    const int quad = lane >> 4, r16 = lane & 15;
    const int m0 = blockIdx.y * 128, n0 = blockIdx.x * 128;

    f32x4 zero = {0.f, 0.f, 0.f, 0.f};
    f32x4 acc[4][4];
#pragma unroll
    for (int i = 0; i < 4; i++)
#pragma unroll
        for (int j = 0; j < 4; j++) acc[i][j] = zero;

    // swizzled staging source pointers (2 rows-of-64 per array)
    const u16* pAh[2]; const u16* pAl[2]; const u16* pBh[2]; const u16* pBl[2];
#pragma unroll
    for (int r = 0; r < 2; r++) {
        int srow = r * 64 + wave * 16 + (lane >> 2);
        int scol = (((lane & 3) ^ ((srow >> 1) & 3))) * 8;
        pAh[r] = Ahg + (size_t)(m0 + srow) * H_ + scol;
        pAl[r] = Alg + (size_t)(m0 + srow) * H_ + scol;
        pBh[r] = Bhg + (size_t)(n0 + srow) * H_ + scol;
        pBl[r] = Blg + (size_t)(n0 + srow) * H_ + scol;
    }
    const int ldsoff = wave * 1024 + lane * 16;   // bytes
    char* lAh = (char*)Ah + ldsoff;
    char* lAl = (char*)Al + ldsoff;
    char* lBh = (char*)Bh + ldsoff;
    char* lBl = (char*)Bl + ldsoff;

    const int aswz = (r16 >> 1) & 3;

    for (int k0 = 0; k0 < H_; k0 += 32) {
        __syncthreads();
#pragma unroll
        for (int r = 0; r < 2; r++) {
            GLOAD_LDS16(pAh[r] + k0, lAh + r * 4096);
            GLOAD_LDS16(pAl[r] + k0, lAl + r * 4096);
            GLOAD_LDS16(pBh[r] + k0, lBh + r * 4096);
            GLOAD_LDS16(pBl[r] + k0, lBl + r * 4096);
        }
        __syncthreads();

        bf16x8 afh[4], afl[4], bfh[4], bfl[4];
#pragma unroll
        for (int i = 0; i < 4; i++) {
            int ar = (wr * 64 + i * 16 + r16) * 32 + ((quad ^ aswz) * 8);
            int br = (wc * 64 + i * 16 + r16) * 32 + ((quad ^ aswz) * 8);
            afh[i] = *(const bf16x8*)&Ah[ar];
            afl[i] = *(const bf16x8*)&Al[ar];
            bfh[i] = *(const bf16x8*)&Bh[br];
            bfl[i] = *(const bf16x8*)&Bl[br];
        }
#pragma unroll
        for (int i = 0; i < 4; i++)
#pragma unroll
            for (int j = 0; j < 4; j++) {
                acc[i][j] = __builtin_amdgcn_mfma_f32_16x16x32_bf16(afh[i], bfh[j], acc[i][j], 0, 0, 0);
                acc[i][j] = __builtin_amdgcn_mfma_f32_16x16x32_bf16(afh[i], bfl[j], acc[i][j], 0, 0, 0);
                acc[i][j] = __builtin_amdgcn_mfma_f32_16x16x32_bf16(afl[i], bfh[j], acc[i][j], 0, 0, 0);
            }
    }

    // C/D layout: row = quad*4 + reg, col = lane&15
#pragma unroll
    for (int i = 0; i < 4; i++) {
        int gm = m0 + wr * 64 + i * 16 + quad * 4;
#pragma unroll
        for (int j = 0; j < 4; j++) {
            int gn = n0 + wc * 64 + j * 16 + r16;
            if (gn < DP1) {
#pragma unroll
                for (int reg = 0; reg < 4; reg++)
                    C[(size_t)(gm + reg) * DP1 + gn] = acc[i][j][reg];
            }
        }
    }
}

// ---------- softmax over DP1, one block per row, in-place; optional bf16 emit ----------
__global__ __launch_bounds__(256)
void softmax_k(float* __restrict__ sim, u16* __restrict__ simb) {
    __shared__ float buf[DP1];
    __shared__ float red[8];
    const int tid = threadIdx.x;
    const int row = blockIdx.x;
    float* rowp = sim + (size_t)row * DP1;

    float mx = -3.4e38f;
    for (int i = tid; i < DP1; i += 256) { float v = rowp[i]; buf[i] = v; mx = fmaxf(mx, v); }
#pragma unroll
    for (int off = 32; off; off >>= 1) mx = fmaxf(mx, __shfl_down(mx, off, 64));
    if ((tid & 63) == 0) red[tid >> 6] = mx;
    __syncthreads();
    if (tid == 0) red[0] = fmaxf(fmaxf(red[0], red[1]), fmaxf(red[2], red[3]));
    __syncthreads();
    mx = red[0];
    __syncthreads();

    float s = 0.f;
    for (int i = tid; i < DP1; i += 256) { float e = __expf(buf[i] - mx); buf[i] = e; s += e; }
#pragma unroll
    for (int off = 32; off; off >>= 1) s += __shfl_down(s, off, 64);
    if ((tid & 63) == 0) red[tid >> 6] = s;
    __syncthreads();
    if (tid == 0) red[0] = red[0] + red[1] + red[2] + red[3];
    __syncthreads();
    float inv = 1.f / red[0];
    if (simb) {
        u16* sbp = simb + (size_t)row * KTP;
        for (int i = tid; i < DP1; i += 256) {
            float p = buf[i] * inv;
            rowp[i] = p;
            sbp[i] = (i < D_) ? f2bf(p) : (u16)0;   // default slot handled in epilogue
        }
        for (int i = DP1 + tid; i < KTP; i += 256) sbp[i] = 0;
    } else {
        for (int i = tid; i < DP1; i += 256) rowp[i] = buf[i] * inv;
    }
}

// ---------- transpose vocab fp32 [D_][H_] -> vocab_t bf16 [H_][KTP] (pad cols = 0) ----------
__global__ __launch_bounds__(256)
void transpose_k(const float* __restrict__ vocab, u16* __restrict__ vt) {
    __shared__ u16 t[32][33];
    int d0 = blockIdx.x * 32, h0 = blockIdx.y * 32;
    int c = threadIdx.x & 31, r = threadIdx.x >> 5;   // r in 0..7
#pragma unroll
    for (int rr = 0; rr < 32; rr += 8) {
        int d = d0 + r + rr;
        float x = (d < D_) ? vocab[(size_t)d * H_ + h0 + c] : 0.f;
        t[r + rr][c] = f2bf(x);
    }
    __syncthreads();
#pragma unroll
    for (int rr = 0; rr < 32; rr += 8) {
        int h = h0 + r + rr;
        vt[(size_t)h * KTP + d0 + c] = t[c][r + rr];
    }
}

// ---------- GEMM2 split-K: P[z] = simb @ vt^T over K-chunk z ----------
// A: simb bf16 [4096][KTP]; B: vt bf16 [H_][KTP]; P: fp32 [4][4096][1024]
__global__ __launch_bounds__(256, 2)
void gemm2_splitk_k(const u16* __restrict__ simb, const u16* __restrict__ vt,
                    float* __restrict__ P) {
    __shared__ u16 As[128 * 32], Bs[128 * 32];

    const int tid  = threadIdx.x;
    const int wave = tid >> 6, lane = tid & 63;
    const int wr = wave >> 1, wc = wave & 1;
    const int quad = lane >> 4, r16 = lane & 15;
    const int m0 = blockIdx.y * 128, n0 = blockIdx.x * 128;
    const int kbeg = blockIdx.z * KCH;
    const int kend = min(KTP, kbeg + KCH);

    f32x4 zero = {0.f, 0.f, 0.f, 0.f};
    f32x4 acc[4][4];
#pragma unroll
    for (int i = 0; i < 4; i++)
#pragma unroll
        for (int j = 0; j < 4; j++) acc[i][j] = zero;

    const u16* pA[2]; const u16* pB[2];
#pragma unroll
    for (int r = 0; r < 2; r++) {
        int srow = r * 64 + wave * 16 + (lane >> 2);
        int scol = (((lane & 3) ^ ((srow >> 1) & 3))) * 8;
        pA[r] = simb + (size_t)(m0 + srow) * KTP + scol;
        pB[r] = vt   + (size_t)(n0 + srow) * KTP + scol;
    }
    const int ldsoff = wave * 1024 + lane * 16;
    char* lA = (char*)As + ldsoff;
    char* lB = (char*)Bs + ldsoff;
    const int aswz = (r16 >> 1) & 3;

    for (int k0 = kbeg; k0 < kend; k0 += 32) {
        __syncthreads();
#pragma unroll
        for (int r = 0; r < 2; r++) {
            GLOAD_LDS16(pA[r] + k0, lA + r * 4096);
            GLOAD_LDS16(pB[r] + k0, lB + r * 4096);
        }
        __syncthreads();

        bf16x8 af[4], bf[4];
#pragma unroll
        for (int i = 0; i < 4; i++) {
            af[i] = *(const bf16x8*)&As[(wr * 64 + i * 16 + r16) * 32 + ((quad ^ aswz) * 8)];
            bf[i] = *(const bf16x8*)&Bs[(wc * 64 + i * 16 + r16) * 32 + ((quad ^ aswz) * 8)];
        }
#pragma unroll
        for (int i = 0; i < 4; i++)
#pragma unroll
            for (int j = 0; j < 4; j++)
                acc[i][j] = __builtin_amdgcn_mfma_f32_16x16x32_bf16(af[i], bf[j], acc[i][j], 0, 0, 0);
    }

    float* Pz = P + (size_t)blockIdx.z * BL * H_;
#pragma unroll
    for (int i = 0; i < 4; i++) {
        int gm0 = m0 + wr * 64 + i * 16 + quad * 4;
#pragma unroll
        for (int reg = 0; reg < 4; reg++) {
            int m = gm0 + reg;
#pragma unroll
            for (int j = 0; j < 4; j++) {
                int gn = n0 + wc * 64 + j * 16 + r16;
                Pz[(size_t)m * H_ + gn] = acc[i][j][reg];
            }
        }
    }
}

// ---------- reduce: out = sum_z P[z] + sim[:,D_]*desc ----------
__global__ __launch_bounds__(256)
void reduce_out_k(const float* __restrict__ P, const float* __restrict__ sim,
                  const float* __restrict__ desc, float* __restrict__ out) {
    size_t idx = ((size_t)blockIdx.x * 256 + threadIdx.x) * 4;   // over BL*H_
    int m = (int)(idx >> 10);
    float w = sim[(size_t)m * DP1 + D_];
    f32x4 p0 = *(const f32x4*)(P + idx);
    f32x4 p1 = *(const f32x4*)(P + (size_t)BL * H_ + idx);
    f32x4 p2 = *(const f32x4*)(P + 2 * (size_t)BL * H_ + idx);
    f32x4 p3 = *(const f32x4*)(P + 3 * (size_t)BL * H_ + idx);
    f32x4 d  = *(const f32x4*)(desc + idx);
    f32x4 r  = p0 + p1 + p2 + p3 + w * d;
    *(f32x4*)(out + idx) = r;
}

// ---------- GEMM2 single-pass (fallback if ws too small for split-K) ----------
__global__ __launch_bounds__(256, 2)
void gemm2_big_k(const u16* __restrict__ simb, const u16* __restrict__ vt,
                 const float* __restrict__ sim, const float* __restrict__ desc,
                 float* __restrict__ out) {
    __shared__ u16 As[128 * 32], Bs[128 * 32];

    const int tid  = threadIdx.x;
    const int wave = tid >> 6, lane = tid & 63;
    const int wr = wave >> 1, wc = wave & 1;
    const int quad = lane >> 4, r16 = lane & 15;
    const int m0 = blockIdx.y * 128, n0 = blockIdx.x * 128;

    f32x4 zero = {0.f, 0.f, 0.f, 0.f};
    f32x4 acc[4][4];
#pragma unroll
    for (int i = 0; i < 4; i++)
#pragma unroll
        for (int j = 0; j < 4; j++) acc[i][j] = zero;

    const u16* pA[2]; const u16* pB[2];
#pragma unroll
    for (int r = 0; r < 2; r++) {
        int srow = r * 64 + wave * 16 + (lane >> 2);
        int scol = (((lane & 3) ^ ((srow >> 1) & 3))) * 8;
        pA[r] = simb + (size_t)(m0 + srow) * KTP + scol;
        pB[r] = vt   + (size_t)(n0 + srow) * KTP + scol;
    }
    const int ldsoff = wave * 1024 + lane * 16;
    char* lA = (char*)As + ldsoff;
    char* lB = (char*)Bs + ldsoff;
    const int aswz = (r16 >> 1) & 3;

    for (int k0 = 0; k0 < KTP; k0 += 32) {
        __syncthreads();
#pragma unroll
        for (int r = 0; r < 2; r++) {
            GLOAD_LDS16(pA[r] + k0, lA + r * 4096);
            GLOAD_LDS16(pB[r] + k0, lB + r * 4096);
        }
        __syncthreads();

        bf16x8 af[4], bf[4];
#pragma unroll
        for (int i = 0; i < 4; i++) {
            af[i] = *(const bf16x8*)&As[(wr * 64 + i * 16 + r16) * 32 + ((quad ^ aswz) * 8)];
            bf[i] = *(const bf16x8*)&Bs[(wc * 64 + i * 16 + r16) * 32 + ((quad ^ aswz) * 8)];
        }
#pragma unroll
        for (int i = 0; i < 4; i++)
#pragma unroll
            for (int j = 0; j < 4; j++)
                acc[i][j] = __builtin_amdgcn_mfma_f32_16x16x32_bf16(af[i], bf[j], acc[i][j], 0, 0, 0);
    }

#pragma unroll
    for (int i = 0; i < 4; i++) {
        int gm0 = m0 + wr * 64 + i * 16 + quad * 4;
#pragma unroll
        for (int reg = 0; reg < 4; reg++) {
            int m = gm0 + reg;
            float w = sim[(size_t)m * DP1 + D_];
#pragma unroll
            for (int j = 0; j < 4; j++) {
                int gn = n0 + wc * 64 + j * 16 + r16;
                out[(size_t)m * H_ + gn] = acc[i][j][reg] + w * desc[(size_t)m * H_ + gn];
            }
        }
    }
}

// ---------- fallback (ws too small): exact fp32, slow but correct ----------
__global__ __launch_bounds__(256)
void naive_logits_k(const float* __restrict__ vocab, const float* __restrict__ desc,
                    const float* __restrict__ defe, float* __restrict__ sim) {
    int d = blockIdx.x * 256 + threadIdx.x;
    if (d >= DP1) return;
    const float* vr = (d < D_) ? (vocab + (size_t)d * H_) : defe;
    const float* dr = desc + (size_t)blockIdx.y * H_;
    float s = 0.f;
    for (int h = 0; h < H_; h++) s = fmaf(dr[h], vr[h], s);
    sim[(size_t)blockIdx.y * DP1 + d] = s;
}

__global__ __launch_bounds__(256)
void naive_out_k(const float* __restrict__ vocab, const float* __restrict__ desc,
                 const float* __restrict__ sim, float* __restrict__ out) {
    int h = blockIdx.x * 256 + threadIdx.x;
    int bl = blockIdx.y;
    const float* sr = sim + (size_t)bl * DP1;
    float s = 0.f;
    for (int d = 0; d < D_; d++) s = fmaf(sr[d], vocab[(size_t)d * H_ + h], s);
    s += sr[D_] * desc[(size_t)bl * H_ + h];
    out[(size_t)bl * H_ + h] = s;
}

extern "C" void kernel_launch(void* const* d_in, const int* in_sizes, int n_in,
                              void* d_out, int out_size, void* d_ws, size_t ws_size,
                              hipStream_t stream) {
    (void)in_sizes; (void)n_in; (void)out_size;
    const float* vocab = (const float*)d_in[0];
    const float* desc  = (const float*)d_in[1];
    const float* defe  = (const float*)d_in[2];
    float* out = (float*)d_out;                          // concept: [4096][1024]
    float* sim = out + (size_t)BL * H_;                  // sim:     [4096][10001]

    // Phase-1 ws layout (bytes):
    //   desc_hi @ 0          (8,388,608)
    //   desc_lo @ 8,388,608  (8,388,608)
    //   fv_hi   @ 16,777,216 (20,709,376 = NPAD*H_*2)
    //   fv_lo   @ 37,486,592 (20,709,376)          -> REQ1 = 58,195,968
    // Phase-2 (after gemm1, phase-1 arrays dead):
    //   vocab_t @ 0          (20,512,768 = H_*KTP*2)
    //   simb    @ 20,512,768 (82,051,072 = BL*KTP*2) -> REQ2 = 102,563,840
    //   P       @ 102,563,840 (67,108,864 = 4*BL*H_*4) -> REQ3 = 169,672,704
    const size_t REQ1 = 58195968ull;
    const size_t REQ2 = 102563840ull;
    const size_t REQ3 = 169672704ull;
    char* ws = (char*)d_ws;

    if (ws_size >= REQ2) {
        u16* dhi  = (u16*)(ws + 0);
        u16* dlo  = (u16*)(ws + 8388608);
        u16* fhi  = (u16*)(ws + 16777216);
        u16* flo  = (u16*)(ws + 37486592);
        u16* vt   = (u16*)(ws + 0);
        u16* simb = (u16*)(ws + 20512768);

        split_desc_k<<<16384, 256, 0, stream>>>(desc, dhi, dlo);
        split_fv_k<<<40448, 256, 0, stream>>>(vocab, defe, fhi, flo);
        gemm1_k<<<dim3(79, 32), 256, 0, stream>>>(dhi, dlo, fhi, flo, sim);
        softmax_k<<<4096, 256, 0, stream>>>(sim, simb);
        transpose_k<<<dim3(313, 32), 256, 0, stream>>>(vocab, vt);
        if (ws_size >= REQ3) {
            float* P = (float*)(ws + 102563840);
            gemm2_splitk_k<<<dim3(8, 32, 4), 256, 0, stream>>>(simb, vt, P);
            reduce_out_k<<<4096, 256, 0, stream>>>(P, sim, desc, out);
        } else {
            gemm2_big_k<<<dim3(8, 32), 256, 0, stream>>>(simb, vt, sim, desc, out);
        }
    } else if (ws_size >= REQ1) {
        u16* dhi = (u16*)(ws + 0);
        u16* dlo = (u16*)(ws + 8388608);
        u16* fhi = (u16*)(ws + 16777216);
        u16* flo = (u16*)(ws + 37486592);
        u16* vt  = (u16*)(ws + 0);

        split_desc_k<<<16384, 256, 0, stream>>>(desc, dhi, dlo);
        split_fv_k<<<40448, 256, 0, stream>>>(vocab, defe, fhi, flo);
        gemm1_k<<<dim3(79, 32), 256, 0, stream>>>(dhi, dlo, fhi, flo, sim);
        softmax_k<<<4096, 256, 0, stream>>>(sim, (u16*)nullptr);
        transpose_k<<<dim3(313, 32), 256, 0, stream>>>(vocab, vt);
        gemm2_big_k<<<dim3(8, 32), 256, 0, stream>>>(
            (const u16*)nullptr, vt, sim, desc, out);  // unreachable in practice
    } else {
        naive_logits_k<<<dim3(40, BL), 256, 0, stream>>>(vocab, desc, defe, sim);
        softmax_k<<<4096, 256, 0, stream>>>(sim, (u16*)nullptr);
        naive_out_k<<<dim3(4, BL), 256, 0, stream>>>(vocab, desc, sim, out);
    }
}

// Round 4
// 820.600 us; speedup vs baseline: 2.1890x; 1.0031x over previous
//
#include <hip/hip_runtime.h>
#include <stdint.h>

#define D_   10000
#define DP1  10001
#define NPAD 10112       // 79 * 128  (padded vocab rows for GEMM1)
#define H_   1024
#define BL   4096        // B * L
#define KTP  10016       // 313 * 32  (padded K for GEMM2)
#define KCH  2528        // split-K chunk (79 K-steps); 4 chunks cover KTP

typedef float  f32x4  __attribute__((ext_vector_type(4)));
typedef __bf16 bf16x8 __attribute__((ext_vector_type(8)));
typedef unsigned short u16;
typedef u16    u16x8  __attribute__((ext_vector_type(8)));

// ---------- bf16 helpers (round-to-nearest-even) ----------
__device__ __forceinline__ u16 f2bf(float x) {
    union { float f; unsigned u; } v; v.f = x;
    unsigned r = v.u + 0x7FFFu + ((v.u >> 16) & 1u);
    return (u16)(r >> 16);
}
__device__ __forceinline__ float bf2f(u16 b) {
    union { float f; unsigned u; } v; v.u = ((unsigned)b) << 16;
    return v.f;
}

// async global -> LDS, 16B per lane (HW: wave-uniform base + lane*16)
#define GLOAD_LDS16(gsrc, ldst)                                             \
    __builtin_amdgcn_global_load_lds(                                       \
        (__attribute__((address_space(1))) void*)(void*)(gsrc),             \
        (__attribute__((address_space(3))) void*)(void*)(ldst), 16, 0, 0)

// LDS chunk swizzle: physical 16B-chunk p at row r holds logical chunk p ^ ((r>>1)&3).
// Staging permutes the GLOBAL source per lane; fragment reads XOR the quad index.
// Verified round 3: SQ_LDS_BANK_CONFLICT 2.07e7 -> 0.

// Double-buffer K-loop (round 4): per iter, the pre-barrier vmcnt(0) drains
// loads issued BEFORE the previous compute phase (~1500 cyc in flight), so the
// structural m97 barrier-drain stall is hidden. One barrier per iter.

// ---------- prep: split fp32 -> bf16 hi + lo ----------
__global__ __launch_bounds__(256)
void split_desc_k(const float* __restrict__ desc, u16* __restrict__ hi, u16* __restrict__ lo) {
    size_t i = (size_t)blockIdx.x * 256 + threadIdx.x;   // exactly BL*H_
    float x = desc[i];
    u16 h = f2bf(x);
    hi[i] = h;
    lo[i] = f2bf(x - bf2f(h));
}

__global__ __launch_bounds__(256)
void split_fv_k(const float* __restrict__ vocab, const float* __restrict__ defe,
                u16* __restrict__ hi, u16* __restrict__ lo) {
    size_t i = (size_t)blockIdx.x * 256 + threadIdx.x;   // exactly NPAD*H_
    int d = (int)(i >> 10);
    int h = (int)(i & 1023);
    float x = 0.f;
    if (d < D_)       x = vocab[i];
    else if (d == D_) x = defe[h];
    u16 hh = f2bf(x);
    hi[i] = hh;
    lo[i] = f2bf(x - bf2f(hh));
}

// ---------- GEMM1: logits = desc @ full_vocab^T, bf16 hi/lo split (3 MFMAs) ----------
__global__ __launch_bounds__(256, 2)
void gemm1_k(const u16* __restrict__ Ahg, const u16* __restrict__ Alg,
             const u16* __restrict__ Bhg, const u16* __restrict__ Blg,
             float* __restrict__ C) {
    __shared__ u16 Ah[2][128 * 32], Al[2][128 * 32], Bh[2][128 * 32], Bl[2][128 * 32];

    const int tid  = threadIdx.x;
    const int wave = tid >> 6, lane = tid & 63;
    const int wr = wave >> 1, wc = wave & 1;
    const int quad = lane >> 4, r16 = lane & 15;
    const int m0 = blockIdx.y * 128, n0 = blockIdx.x * 128;

    f32x4 zero = {0.f, 0.f, 0.f, 0.f};
    f32x4 acc[4][4];
#pragma unroll
    for (int i = 0; i < 4; i++)
#pragma unroll
        for (int j = 0; j < 4; j++) acc[i][j] = zero;

    // swizzled staging source pointers (2 rows-of-64 per array)
    const u16* pAh[2]; const u16* pAl[2]; const u16* pBh[2]; const u16* pBl[2];
#pragma unroll
    for (int r = 0; r < 2; r++) {
        int srow = r * 64 + wave * 16 + (lane >> 2);
        int scol = (((lane & 3) ^ ((srow >> 1) & 3))) * 8;
        pAh[r] = Ahg + (size_t)(m0 + srow) * H_ + scol;
        pAl[r] = Alg + (size_t)(m0 + srow) * H_ + scol;
        pBh[r] = Bhg + (size_t)(n0 + srow) * H_ + scol;
        pBl[r] = Blg + (size_t)(n0 + srow) * H_ + scol;
    }
    const int ldsoff = wave * 1024 + lane * 16;   // bytes within one buffer
    const int aswz = (r16 >> 1) & 3;

    auto stage = [&](int k0, int b) {
#pragma unroll
        for (int r = 0; r < 2; r++) {
            GLOAD_LDS16(pAh[r] + k0, (char*)Ah[b] + ldsoff + r * 4096);
            GLOAD_LDS16(pAl[r] + k0, (char*)Al[b] + ldsoff + r * 4096);
            GLOAD_LDS16(pBh[r] + k0, (char*)Bh[b] + ldsoff + r * 4096);
            GLOAD_LDS16(pBl[r] + k0, (char*)Bl[b] + ldsoff + r * 4096);
        }
    };

    stage(0, 0);   // prologue
    for (int it = 0; it < 32; it++) {
        __syncthreads();                       // drains loads issued one compute-phase ago
        if (it + 1 < 32) stage((it + 1) * 32, (it + 1) & 1);
        const int b = it & 1;

        bf16x8 afh[4], afl[4], bfh[4], bfl[4];
#pragma unroll
        for (int i = 0; i < 4; i++) {
            int ar = (wr * 64 + i * 16 + r16) * 32 + ((quad ^ aswz) * 8);
            int br = (wc * 64 + i * 16 + r16) * 32 + ((quad ^ aswz) * 8);
            afh[i] = *(const bf16x8*)&Ah[b][ar];
            afl[i] = *(const bf16x8*)&Al[b][ar];
            bfh[i] = *(const bf16x8*)&Bh[b][br];
            bfl[i] = *(const bf16x8*)&Bl[b][br];
        }
#pragma unroll
        for (int i = 0; i < 4; i++)
#pragma unroll
            for (int j = 0; j < 4; j++) {
                acc[i][j] = __builtin_amdgcn_mfma_f32_16x16x32_bf16(afh[i], bfh[j], acc[i][j], 0, 0, 0);
                acc[i][j] = __builtin_amdgcn_mfma_f32_16x16x32_bf16(afh[i], bfl[j], acc[i][j], 0, 0, 0);
                acc[i][j] = __builtin_amdgcn_mfma_f32_16x16x32_bf16(afl[i], bfh[j], acc[i][j], 0, 0, 0);
            }
    }

    // C/D layout: row = quad*4 + reg, col = lane&15
#pragma unroll
    for (int i = 0; i < 4; i++) {
        int gm = m0 + wr * 64 + i * 16 + quad * 4;
#pragma unroll
        for (int j = 0; j < 4; j++) {
            int gn = n0 + wc * 64 + j * 16 + r16;
            if (gn < DP1) {
#pragma unroll
                for (int reg = 0; reg < 4; reg++)
                    C[(size_t)(gm + reg) * DP1 + gn] = acc[i][j][reg];
            }
        }
    }
}

// ---------- softmax over DP1, one block per row, in-place; optional bf16 emit ----------
__global__ __launch_bounds__(256)
void softmax_k(float* __restrict__ sim, u16* __restrict__ simb) {
    __shared__ float buf[DP1];
    __shared__ float red[8];
    const int tid = threadIdx.x;
    const int row = blockIdx.x;
    float* rowp = sim + (size_t)row * DP1;

    float mx = -3.4e38f;
    for (int i = tid; i < DP1; i += 256) { float v = rowp[i]; buf[i] = v; mx = fmaxf(mx, v); }
#pragma unroll
    for (int off = 32; off; off >>= 1) mx = fmaxf(mx, __shfl_down(mx, off, 64));
    if ((tid & 63) == 0) red[tid >> 6] = mx;
    __syncthreads();
    if (tid == 0) red[0] = fmaxf(fmaxf(red[0], red[1]), fmaxf(red[2], red[3]));
    __syncthreads();
    mx = red[0];
    __syncthreads();

    float s = 0.f;
    for (int i = tid; i < DP1; i += 256) { float e = __expf(buf[i] - mx); buf[i] = e; s += e; }
#pragma unroll
    for (int off = 32; off; off >>= 1) s += __shfl_down(s, off, 64);
    if ((tid & 63) == 0) red[tid >> 6] = s;
    __syncthreads();
    if (tid == 0) red[0] = red[0] + red[1] + red[2] + red[3];
    __syncthreads();
    float inv = 1.f / red[0];
    if (simb) {
        u16* sbp = simb + (size_t)row * KTP;
        for (int i = tid; i < DP1; i += 256) {
            float p = buf[i] * inv;
            rowp[i] = p;
            sbp[i] = (i < D_) ? f2bf(p) : (u16)0;   // default slot handled in epilogue
        }
        for (int i = DP1 + tid; i < KTP; i += 256) sbp[i] = 0;
    } else {
        for (int i = tid; i < DP1; i += 256) rowp[i] = buf[i] * inv;
    }
}

// ---------- transpose vocab fp32 [D_][H_] -> vocab_t bf16 [H_][KTP] (pad cols = 0) ----------
__global__ __launch_bounds__(256)
void transpose_k(const float* __restrict__ vocab, u16* __restrict__ vt) {
    __shared__ u16 t[32][33];
    int d0 = blockIdx.x * 32, h0 = blockIdx.y * 32;
    int c = threadIdx.x & 31, r = threadIdx.x >> 5;   // r in 0..7
#pragma unroll
    for (int rr = 0; rr < 32; rr += 8) {
        int d = d0 + r + rr;
        float x = (d < D_) ? vocab[(size_t)d * H_ + h0 + c] : 0.f;
        t[r + rr][c] = f2bf(x);
    }
    __syncthreads();
#pragma unroll
    for (int rr = 0; rr < 32; rr += 8) {
        int h = h0 + r + rr;
        vt[(size_t)h * KTP + d0 + c] = t[c][r + rr];
    }
}

// ---------- GEMM2 split-K: P[z] = simb @ vt^T over K-chunk z ----------
// A: simb bf16 [4096][KTP]; B: vt bf16 [H_][KTP]; P: fp32 [4][4096][1024]
__global__ __launch_bounds__(256, 2)
void gemm2_splitk_k(const u16* __restrict__ simb, const u16* __restrict__ vt,
                    float* __restrict__ P) {
    __shared__ u16 As[2][128 * 32], Bs[2][128 * 32];

    const int tid  = threadIdx.x;
    const int wave = tid >> 6, lane = tid & 63;
    const int wr = wave >> 1, wc = wave & 1;
    const int quad = lane >> 4, r16 = lane & 15;
    const int m0 = blockIdx.y * 128, n0 = blockIdx.x * 128;
    const int kbeg = blockIdx.z * KCH;
    const int kend = min(KTP, kbeg + KCH);
    const int nit = (kend - kbeg) >> 5;

    f32x4 zero = {0.f, 0.f, 0.f, 0.f};
    f32x4 acc[4][4];
#pragma unroll
    for (int i = 0; i < 4; i++)
#pragma unroll
        for (int j = 0; j < 4; j++) acc[i][j] = zero;

    const u16* pA[2]; const u16* pB[2];
#pragma unroll
    for (int r = 0; r < 2; r++) {
        int srow = r * 64 + wave * 16 + (lane >> 2);
        int scol = (((lane & 3) ^ ((srow >> 1) & 3))) * 8;
        pA[r] = simb + (size_t)(m0 + srow) * KTP + scol;
        pB[r] = vt   + (size_t)(n0 + srow) * KTP + scol;
    }
    const int ldsoff = wave * 1024 + lane * 16;
    const int aswz = (r16 >> 1) & 3;

    auto stage = [&](int k0, int b) {
#pragma unroll
        for (int r = 0; r < 2; r++) {
            GLOAD_LDS16(pA[r] + k0, (char*)As[b] + ldsoff + r * 4096);
            GLOAD_LDS16(pB[r] + k0, (char*)Bs[b] + ldsoff + r * 4096);
        }
    };

    stage(kbeg, 0);
    for (int it = 0; it < nit; it++) {
        __syncthreads();
        if (it + 1 < nit) stage(kbeg + (it + 1) * 32, (it + 1) & 1);
        const int b = it & 1;

        bf16x8 af[4], bf[4];
#pragma unroll
        for (int i = 0; i < 4; i++) {
            af[i] = *(const bf16x8*)&As[b][(wr * 64 + i * 16 + r16) * 32 + ((quad ^ aswz) * 8)];
            bf[i] = *(const bf16x8*)&Bs[b][(wc * 64 + i * 16 + r16) * 32 + ((quad ^ aswz) * 8)];
        }
#pragma unroll
        for (int i = 0; i < 4; i++)
#pragma unroll
            for (int j = 0; j < 4; j++)
                acc[i][j] = __builtin_amdgcn_mfma_f32_16x16x32_bf16(af[i], bf[j], acc[i][j], 0, 0, 0);
    }

    float* Pz = P + (size_t)blockIdx.z * BL * H_;
#pragma unroll
    for (int i = 0; i < 4; i++) {
        int gm0 = m0 + wr * 64 + i * 16 + quad * 4;
#pragma unroll
        for (int reg = 0; reg < 4; reg++) {
            int m = gm0 + reg;
#pragma unroll
            for (int j = 0; j < 4; j++) {
                int gn = n0 + wc * 64 + j * 16 + r16;
                Pz[(size_t)m * H_ + gn] = acc[i][j][reg];
            }
        }
    }
}

// ---------- reduce: out = sum_z P[z] + sim[:,D_]*desc ----------
__global__ __launch_bounds__(256)
void reduce_out_k(const float* __restrict__ P, const float* __restrict__ sim,
                  const float* __restrict__ desc, float* __restrict__ out) {
    size_t idx = ((size_t)blockIdx.x * 256 + threadIdx.x) * 4;   // over BL*H_
    int m = (int)(idx >> 10);
    float w = sim[(size_t)m * DP1 + D_];
    f32x4 p0 = *(const f32x4*)(P + idx);
    f32x4 p1 = *(const f32x4*)(P + (size_t)BL * H_ + idx);
    f32x4 p2 = *(const f32x4*)(P + 2 * (size_t)BL * H_ + idx);
    f32x4 p3 = *(const f32x4*)(P + 3 * (size_t)BL * H_ + idx);
    f32x4 d  = *(const f32x4*)(desc + idx);
    f32x4 r  = p0 + p1 + p2 + p3 + w * d;
    *(f32x4*)(out + idx) = r;
}

// ---------- GEMM2 single-pass (fallback if ws too small for split-K) ----------
__global__ __launch_bounds__(256, 2)
void gemm2_big_k(const u16* __restrict__ simb, const u16* __restrict__ vt,
                 const float* __restrict__ sim, const float* __restrict__ desc,
                 float* __restrict__ out) {
    __shared__ u16 As[128 * 32], Bs[128 * 32];

    const int tid  = threadIdx.x;
    const int wave = tid >> 6, lane = tid & 63;
    const int wr = wave >> 1, wc = wave & 1;
    const int quad = lane >> 4, r16 = lane & 15;
    const int m0 = blockIdx.y * 128, n0 = blockIdx.x * 128;

    f32x4 zero = {0.f, 0.f, 0.f, 0.f};
    f32x4 acc[4][4];
#pragma unroll
    for (int i = 0; i < 4; i++)
#pragma unroll
        for (int j = 0; j < 4; j++) acc[i][j] = zero;

    const u16* pA[2]; const u16* pB[2];
#pragma unroll
    for (int r = 0; r < 2; r++) {
        int srow = r * 64 + wave * 16 + (lane >> 2);
        int scol = (((lane & 3) ^ ((srow >> 1) & 3))) * 8;
        pA[r] = simb + (size_t)(m0 + srow) * KTP + scol;
        pB[r] = vt   + (size_t)(n0 + srow) * KTP + scol;
    }
    const int ldsoff = wave * 1024 + lane * 16;
    char* lA = (char*)As + ldsoff;
    char* lB = (char*)Bs + ldsoff;
    const int aswz = (r16 >> 1) & 3;

    for (int k0 = 0; k0 < KTP; k0 += 32) {
        __syncthreads();
#pragma unroll
        for (int r = 0; r < 2; r++) {
            GLOAD_LDS16(pA[r] + k0, lA + r * 4096);
            GLOAD_LDS16(pB[r] + k0, lB + r * 4096);
        }
        __syncthreads();

        bf16x8 af[4], bf[4];
#pragma unroll
        for (int i = 0; i < 4; i++) {
            af[i] = *(const bf16x8*)&As[(wr * 64 + i * 16 + r16) * 32 + ((quad ^ aswz) * 8)];
            bf[i] = *(const bf16x8*)&Bs[(wc * 64 + i * 16 + r16) * 32 + ((quad ^ aswz) * 8)];
        }
#pragma unroll
        for (int i = 0; i < 4; i++)
#pragma unroll
            for (int j = 0; j < 4; j++)
                acc[i][j] = __builtin_amdgcn_mfma_f32_16x16x32_bf16(af[i], bf[j], acc[i][j], 0, 0, 0);
    }

#pragma unroll
    for (int i = 0; i < 4; i++) {
        int gm0 = m0 + wr * 64 + i * 16 + quad * 4;
#pragma unroll
        for (int reg = 0; reg < 4; reg++) {
            int m = gm0 + reg;
            float w = sim[(size_t)m * DP1 + D_];
#pragma unroll
            for (int j = 0; j < 4; j++) {
                int gn = n0 + wc * 64 + j * 16 + r16;
                out[(size_t)m * H_ + gn] = acc[i][j][reg] + w * desc[(size_t)m * H_ + gn];
            }
        }
    }
}

// ---------- fallback (ws too small): exact fp32, slow but correct ----------
__global__ __launch_bounds__(256)
void naive_logits_k(const float* __restrict__ vocab, const float* __restrict__ desc,
                    const float* __restrict__ defe, float* __restrict__ sim) {
    int d = blockIdx.x * 256 + threadIdx.x;
    if (d >= DP1) return;
    const float* vr = (d < D_) ? (vocab + (size_t)d * H_) : defe;
    const float* dr = desc + (size_t)blockIdx.y * H_;
    float s = 0.f;
    for (int h = 0; h < H_; h++) s = fmaf(dr[h], vr[h], s);
    sim[(size_t)blockIdx.y * DP1 + d] = s;
}

__global__ __launch_bounds__(256)
void naive_out_k(const float* __restrict__ vocab, const float* __restrict__ desc,
                 const float* __restrict__ sim, float* __restrict__ out) {
    int h = blockIdx.x * 256 + threadIdx.x;
    int bl = blockIdx.y;
    const float* sr = sim + (size_t)bl * DP1;
    float s = 0.f;
    for (int d = 0; d < D_; d++) s = fmaf(sr[d], vocab[(size_t)d * H_ + h], s);
    s += sr[D_] * desc[(size_t)bl * H_ + h];
    out[(size_t)bl * H_ + h] = s;
}

extern "C" void kernel_launch(void* const* d_in, const int* in_sizes, int n_in,
                              void* d_out, int out_size, void* d_ws, size_t ws_size,
                              hipStream_t stream) {
    (void)in_sizes; (void)n_in; (void)out_size;
    const float* vocab = (const float*)d_in[0];
    const float* desc  = (const float*)d_in[1];
    const float* defe  = (const float*)d_in[2];
    float* out = (float*)d_out;                          // concept: [4096][1024]
    float* sim = out + (size_t)BL * H_;                  // sim:     [4096][10001]

    // Phase-1 ws layout (bytes):
    //   desc_hi @ 0          (8,388,608)
    //   desc_lo @ 8,388,608  (8,388,608)
    //   fv_hi   @ 16,777,216 (20,709,376 = NPAD*H_*2)
    //   fv_lo   @ 37,486,592 (20,709,376)          -> REQ1 = 58,195,968
    // Phase-2 (after gemm1, phase-1 arrays dead):
    //   vocab_t @ 0          (20,512,768 = H_*KTP*2)
    //   simb    @ 20,512,768 (82,051,072 = BL*KTP*2) -> REQ2 = 102,563,840
    //   P       @ 102,563,840 (67,108,864 = 4*BL*H_*4) -> REQ3 = 169,672,704
    const size_t REQ1 = 58195968ull;
    const size_t REQ2 = 102563840ull;
    const size_t REQ3 = 169672704ull;
    char* ws = (char*)d_ws;

    if (ws_size >= REQ2) {
        u16* dhi  = (u16*)(ws + 0);
        u16* dlo  = (u16*)(ws + 8388608);
        u16* fhi  = (u16*)(ws + 16777216);
        u16* flo  = (u16*)(ws + 37486592);
        u16* vt   = (u16*)(ws + 0);
        u16* simb = (u16*)(ws + 20512768);

        split_desc_k<<<16384, 256, 0, stream>>>(desc, dhi, dlo);
        split_fv_k<<<40448, 256, 0, stream>>>(vocab, defe, fhi, flo);
        gemm1_k<<<dim3(79, 32), 256, 0, stream>>>(dhi, dlo, fhi, flo, sim);
        softmax_k<<<4096, 256, 0, stream>>>(sim, simb);
        transpose_k<<<dim3(313, 32), 256, 0, stream>>>(vocab, vt);
        if (ws_size >= REQ3) {
            float* P = (float*)(ws + 102563840);
            gemm2_splitk_k<<<dim3(8, 32, 4), 256, 0, stream>>>(simb, vt, P);
            reduce_out_k<<<4096, 256, 0, stream>>>(P, sim, desc, out);
        } else {
            gemm2_big_k<<<dim3(8, 32), 256, 0, stream>>>(simb, vt, sim, desc, out);
        }
    } else if (ws_size >= REQ1) {
        u16* dhi = (u16*)(ws + 0);
        u16* dlo = (u16*)(ws + 8388608);
        u16* fhi = (u16*)(ws + 16777216);
        u16* flo = (u16*)(ws + 37486592);

        split_desc_k<<<16384, 256, 0, stream>>>(desc, dhi, dlo);
        split_fv_k<<<40448, 256, 0, stream>>>(vocab, defe, fhi, flo);
        gemm1_k<<<dim3(79, 32), 256, 0, stream>>>(dhi, dlo, fhi, flo, sim);
        softmax_k<<<4096, 256, 0, stream>>>(sim, (u16*)nullptr);
        naive_out_k<<<dim3(4, BL), 256, 0, stream>>>(vocab, desc, sim, out);
    } else {
        naive_logits_k<<<dim3(40, BL), 256, 0, stream>>>(vocab, desc, defe, sim);
        softmax_k<<<4096, 256, 0, stream>>>(sim, (u16*)nullptr);
        naive_out_k<<<dim3(4, BL), 256, 0, stream>>>(vocab, desc, sim, out);
    }
}

// Round 5
// 699.527 us; speedup vs baseline: 2.5679x; 1.1731x over previous
//
#include <hip/hip_runtime.h>
#include <stdint.h>

#define D_    10000
#define DP1   10001
#define NPAD2 10240      // 40 * 256 (padded vocab rows for GEMM1, N-tile 256)
#define H_    1024
#define BL    4096       // B * L
#define KTP   10016      // 313 * 32 (padded K for GEMM2)
#define KCH   2528       // split-K chunk; 4 chunks cover KTP

typedef float  f32x4  __attribute__((ext_vector_type(4)));
typedef __bf16 bf16x8 __attribute__((ext_vector_type(8)));
typedef unsigned short u16;
typedef u16    u16x8  __attribute__((ext_vector_type(8)));

// ---------- bf16 helpers (round-to-nearest-even) ----------
__device__ __forceinline__ u16 f2bf(float x) {
    union { float f; unsigned u; } v; v.f = x;
    unsigned r = v.u + 0x7FFFu + ((v.u >> 16) & 1u);
    return (u16)(r >> 16);
}
__device__ __forceinline__ float bf2f(u16 b) {
    union { float f; unsigned u; } v; v.u = ((unsigned)b) << 16;
    return v.f;
}

// async global -> LDS, 16B per lane (HW: wave-uniform base + lane*16)
#define GLOAD_LDS16(gsrc, ldst)                                             \
    __builtin_amdgcn_global_load_lds(                                       \
        (__attribute__((address_space(1))) void*)(void*)(gsrc),             \
        (__attribute__((address_space(3))) void*)(void*)(ldst), 16, 0, 0)

// LDS chunk swizzle: physical 16B-chunk p at row r holds logical chunk p^((r>>1)&3).
// Verified round 3: SQ_LDS_BANK_CONFLICT 2.07e7 -> 0.
// Round 4 lesson: explicit LDS double-buffer regressed (compiler inserts
// conservative vmcnt drains; occupancy halved) -> round-3 2-barrier shape kept.
// Round 5: 128x256 tile / 512 threads — fewer barriers per FLOP, -25% staging.

// ---------- prep: split fp32 -> bf16 hi + lo ----------
__global__ __launch_bounds__(256)
void split_desc_k(const float* __restrict__ desc, u16* __restrict__ hi, u16* __restrict__ lo) {
    size_t i = (size_t)blockIdx.x * 256 + threadIdx.x;   // exactly BL*H_
    float x = desc[i];
    u16 h = f2bf(x);
    hi[i] = h;
    lo[i] = f2bf(x - bf2f(h));
}

__global__ __launch_bounds__(256)
void split_fv_k(const float* __restrict__ vocab, const float* __restrict__ defe,
                u16* __restrict__ hi, u16* __restrict__ lo) {
    size_t i = (size_t)blockIdx.x * 256 + threadIdx.x;   // exactly NPAD2*H_
    int d = (int)(i >> 10);
    int h = (int)(i & 1023);
    float x = 0.f;
    if (d < D_)       x = vocab[i];
    else if (d == D_) x = defe[h];
    u16 hh = f2bf(x);
    hi[i] = hh;
    lo[i] = f2bf(x - bf2f(hh));
}

// ---------- GEMM1: logits = desc @ full_vocab^T, bf16 hi/lo split (3 MFMAs) ----------
// Tile 128(M) x 256(N), BK=32, 512 threads (8 waves, wave grid 2x4, 64x64/wave).
__global__ __launch_bounds__(512, 4)
void gemm1_k(const u16* __restrict__ Ahg, const u16* __restrict__ Alg,
             const u16* __restrict__ Bhg, const u16* __restrict__ Blg,
             float* __restrict__ C) {
    __shared__ u16 Ah[128 * 32], Al[128 * 32], Bh[256 * 32], Bl[256 * 32];  // 48 KB

    const int tid  = threadIdx.x;
    const int wave = tid >> 6, lane = tid & 63;
    const int wr = wave >> 2, wc = wave & 3;
    const int quad = lane >> 4, r16 = lane & 15;
    const int m0 = blockIdx.y * 128, n0 = blockIdx.x * 256;

    f32x4 zero = {0.f, 0.f, 0.f, 0.f};
    f32x4 acc[4][4];
#pragma unroll
    for (int i = 0; i < 4; i++)
#pragma unroll
        for (int j = 0; j < 4; j++) acc[i][j] = zero;

    // staging: thread t covers row t>>2, chunk t&3 (swizzled source column)
    const int arow = tid >> 2, achk = tid & 3;
    const int ascol = (achk ^ ((arow >> 1) & 3)) * 8;
    const u16* a_h = Ahg + (size_t)(m0 + arow) * H_ + ascol;
    const u16* a_l = Alg + (size_t)(m0 + arow) * H_ + ascol;
    const u16* b_h[2]; const u16* b_l[2];
#pragma unroll
    for (int r = 0; r < 2; r++) {
        int brow = r * 128 + arow;
        int bscol = (achk ^ ((brow >> 1) & 3)) * 8;
        b_h[r] = Bhg + (size_t)(n0 + brow) * H_ + bscol;
        b_l[r] = Blg + (size_t)(n0 + brow) * H_ + bscol;
    }
    char* lAh = (char*)Ah + tid * 16;
    char* lAl = (char*)Al + tid * 16;
    char* lBh = (char*)Bh + tid * 16;
    char* lBl = (char*)Bl + tid * 16;
    const int aswz = (r16 >> 1) & 3;

    for (int k0 = 0; k0 < H_; k0 += 32) {
        __syncthreads();
        GLOAD_LDS16(a_h + k0,    lAh);
        GLOAD_LDS16(a_l + k0,    lAl);
        GLOAD_LDS16(b_h[0] + k0, lBh);
        GLOAD_LDS16(b_h[1] + k0, lBh + 8192);
        GLOAD_LDS16(b_l[0] + k0, lBl);
        GLOAD_LDS16(b_l[1] + k0, lBl + 8192);
        __syncthreads();

        bf16x8 afh[4], afl[4], bfh[4], bfl[4];
#pragma unroll
        for (int i = 0; i < 4; i++) {
            int ar = (wr * 64 + i * 16 + r16) * 32 + ((quad ^ aswz) * 8);
            int br = (wc * 64 + i * 16 + r16) * 32 + ((quad ^ aswz) * 8);
            afh[i] = *(const bf16x8*)&Ah[ar];
            afl[i] = *(const bf16x8*)&Al[ar];
            bfh[i] = *(const bf16x8*)&Bh[br];
            bfl[i] = *(const bf16x8*)&Bl[br];
        }
#pragma unroll
        for (int i = 0; i < 4; i++)
#pragma unroll
            for (int j = 0; j < 4; j++) {
                acc[i][j] = __builtin_amdgcn_mfma_f32_16x16x32_bf16(afh[i], bfh[j], acc[i][j], 0, 0, 0);
                acc[i][j] = __builtin_amdgcn_mfma_f32_16x16x32_bf16(afh[i], bfl[j], acc[i][j], 0, 0, 0);
                acc[i][j] = __builtin_amdgcn_mfma_f32_16x16x32_bf16(afl[i], bfh[j], acc[i][j], 0, 0, 0);
            }
    }

    // C/D layout: row = quad*4 + reg, col = lane&15
#pragma unroll
    for (int i = 0; i < 4; i++) {
        int gm = m0 + wr * 64 + i * 16 + quad * 4;
#pragma unroll
        for (int j = 0; j < 4; j++) {
            int gn = n0 + wc * 64 + j * 16 + r16;
            if (gn < DP1) {
#pragma unroll
                for (int reg = 0; reg < 4; reg++)
                    C[(size_t)(gm + reg) * DP1 + gn] = acc[i][j][reg];
            }
        }
    }
}

// ---------- softmax over DP1, one block per row, in-place; optional bf16 emit ----------
__global__ __launch_bounds__(256)
void softmax_k(float* __restrict__ sim, u16* __restrict__ simb) {
    __shared__ float buf[DP1];
    __shared__ float red[8];
    const int tid = threadIdx.x;
    const int row = blockIdx.x;
    float* rowp = sim + (size_t)row * DP1;

    float mx = -3.4e38f;
    for (int i = tid; i < DP1; i += 256) { float v = rowp[i]; buf[i] = v; mx = fmaxf(mx, v); }
#pragma unroll
    for (int off = 32; off; off >>= 1) mx = fmaxf(mx, __shfl_down(mx, off, 64));
    if ((tid & 63) == 0) red[tid >> 6] = mx;
    __syncthreads();
    if (tid == 0) red[0] = fmaxf(fmaxf(red[0], red[1]), fmaxf(red[2], red[3]));
    __syncthreads();
    mx = red[0];
    __syncthreads();

    float s = 0.f;
    for (int i = tid; i < DP1; i += 256) { float e = __expf(buf[i] - mx); buf[i] = e; s += e; }
#pragma unroll
    for (int off = 32; off; off >>= 1) s += __shfl_down(s, off, 64);
    if ((tid & 63) == 0) red[tid >> 6] = s;
    __syncthreads();
    if (tid == 0) red[0] = red[0] + red[1] + red[2] + red[3];
    __syncthreads();
    float inv = 1.f / red[0];
    if (simb) {
        u16* sbp = simb + (size_t)row * KTP;
        for (int i = tid; i < DP1; i += 256) {
            float p = buf[i] * inv;
            rowp[i] = p;
            sbp[i] = (i < D_) ? f2bf(p) : (u16)0;   // default slot handled in epilogue
        }
        for (int i = DP1 + tid; i < KTP; i += 256) sbp[i] = 0;
    } else {
        for (int i = tid; i < DP1; i += 256) rowp[i] = buf[i] * inv;
    }
}

// ---------- transpose vocab fp32 [D_][H_] -> vocab_t bf16 [H_][KTP] (pad cols = 0) ----------
__global__ __launch_bounds__(256)
void transpose_k(const float* __restrict__ vocab, u16* __restrict__ vt) {
    __shared__ u16 t[32][33];
    int d0 = blockIdx.x * 32, h0 = blockIdx.y * 32;
    int c = threadIdx.x & 31, r = threadIdx.x >> 5;   // r in 0..7
#pragma unroll
    for (int rr = 0; rr < 32; rr += 8) {
        int d = d0 + r + rr;
        float x = (d < D_) ? vocab[(size_t)d * H_ + h0 + c] : 0.f;
        t[r + rr][c] = f2bf(x);
    }
    __syncthreads();
#pragma unroll
    for (int rr = 0; rr < 32; rr += 8) {
        int h = h0 + r + rr;
        vt[(size_t)h * KTP + d0 + c] = t[c][r + rr];
    }
}

// ---------- GEMM2 split-K: P[z] = simb @ vt^T over K-chunk z ----------
// Tile 128(M) x 256(N over H), BK=32, 512 threads. Grid (4, 32, 4).
__global__ __launch_bounds__(512, 4)
void gemm2_splitk_k(const u16* __restrict__ simb, const u16* __restrict__ vt,
                    float* __restrict__ P) {
    __shared__ u16 As[128 * 32], Bs[256 * 32];   // 24 KB

    const int tid  = threadIdx.x;
    const int wave = tid >> 6, lane = tid & 63;
    const int wr = wave >> 2, wc = wave & 3;
    const int quad = lane >> 4, r16 = lane & 15;
    const int m0 = blockIdx.y * 128, n0 = blockIdx.x * 256;
    const int kbeg = blockIdx.z * KCH;
    const int kend = min(KTP, kbeg + KCH);

    f32x4 zero = {0.f, 0.f, 0.f, 0.f};
    f32x4 acc[4][4];
#pragma unroll
    for (int i = 0; i < 4; i++)
#pragma unroll
        for (int j = 0; j < 4; j++) acc[i][j] = zero;

    const int arow = tid >> 2, achk = tid & 3;
    const int ascol = (achk ^ ((arow >> 1) & 3)) * 8;
    const u16* a_s = simb + (size_t)(m0 + arow) * KTP + ascol;
    const u16* b_s[2];
#pragma unroll
    for (int r = 0; r < 2; r++) {
        int brow = r * 128 + arow;
        int bscol = (achk ^ ((brow >> 1) & 3)) * 8;
        b_s[r] = vt + (size_t)(n0 + brow) * KTP + bscol;
    }
    char* lA = (char*)As + tid * 16;
    char* lB = (char*)Bs + tid * 16;
    const int aswz = (r16 >> 1) & 3;

    for (int k0 = kbeg; k0 < kend; k0 += 32) {
        __syncthreads();
        GLOAD_LDS16(a_s + k0,    lA);
        GLOAD_LDS16(b_s[0] + k0, lB);
        GLOAD_LDS16(b_s[1] + k0, lB + 8192);
        __syncthreads();

        bf16x8 af[4], bf[4];
#pragma unroll
        for (int i = 0; i < 4; i++) {
            af[i] = *(const bf16x8*)&As[(wr * 64 + i * 16 + r16) * 32 + ((quad ^ aswz) * 8)];
            bf[i] = *(const bf16x8*)&Bs[(wc * 64 + i * 16 + r16) * 32 + ((quad ^ aswz) * 8)];
        }
#pragma unroll
        for (int i = 0; i < 4; i++)
#pragma unroll
            for (int j = 0; j < 4; j++)
                acc[i][j] = __builtin_amdgcn_mfma_f32_16x16x32_bf16(af[i], bf[j], acc[i][j], 0, 0, 0);
    }

    float* Pz = P + (size_t)blockIdx.z * BL * H_;
#pragma unroll
    for (int i = 0; i < 4; i++) {
        int gm0 = m0 + wr * 64 + i * 16 + quad * 4;
#pragma unroll
        for (int reg = 0; reg < 4; reg++) {
            int m = gm0 + reg;
#pragma unroll
            for (int j = 0; j < 4; j++) {
                int gn = n0 + wc * 64 + j * 16 + r16;
                Pz[(size_t)m * H_ + gn] = acc[i][j][reg];
            }
        }
    }
}

// ---------- reduce: out = sum_z P[z] + sim[:,D_]*desc ----------
__global__ __launch_bounds__(256)
void reduce_out_k(const float* __restrict__ P, const float* __restrict__ sim,
                  const float* __restrict__ desc, float* __restrict__ out) {
    size_t idx = ((size_t)blockIdx.x * 256 + threadIdx.x) * 4;   // over BL*H_
    int m = (int)(idx >> 10);
    float w = sim[(size_t)m * DP1 + D_];
    f32x4 p0 = *(const f32x4*)(P + idx);
    f32x4 p1 = *(const f32x4*)(P + (size_t)BL * H_ + idx);
    f32x4 p2 = *(const f32x4*)(P + 2 * (size_t)BL * H_ + idx);
    f32x4 p3 = *(const f32x4*)(P + 3 * (size_t)BL * H_ + idx);
    f32x4 d  = *(const f32x4*)(desc + idx);
    f32x4 r  = p0 + p1 + p2 + p3 + w * d;
    *(f32x4*)(out + idx) = r;
}

// ---------- GEMM2 single-pass (fallback if ws too small for split-K) ----------
__global__ __launch_bounds__(256, 2)
void gemm2_big_k(const u16* __restrict__ simb, const u16* __restrict__ vt,
                 const float* __restrict__ sim, const float* __restrict__ desc,
                 float* __restrict__ out) {
    __shared__ u16 As[128 * 32], Bs[128 * 32];

    const int tid  = threadIdx.x;
    const int wave = tid >> 6, lane = tid & 63;
    const int wr = wave >> 1, wc = wave & 1;
    const int quad = lane >> 4, r16 = lane & 15;
    const int m0 = blockIdx.y * 128, n0 = blockIdx.x * 128;

    f32x4 zero = {0.f, 0.f, 0.f, 0.f};
    f32x4 acc[4][4];
#pragma unroll
    for (int i = 0; i < 4; i++)
#pragma unroll
        for (int j = 0; j < 4; j++) acc[i][j] = zero;

    const u16* pA[2]; const u16* pB[2];
#pragma unroll
    for (int r = 0; r < 2; r++) {
        int srow = r * 64 + wave * 16 + (lane >> 2);
        int scol = (((lane & 3) ^ ((srow >> 1) & 3))) * 8;
        pA[r] = simb + (size_t)(m0 + srow) * KTP + scol;
        pB[r] = vt   + (size_t)(n0 + srow) * KTP + scol;
    }
    const int ldsoff = wave * 1024 + lane * 16;
    char* lA = (char*)As + ldsoff;
    char* lB = (char*)Bs + ldsoff;
    const int aswz = (r16 >> 1) & 3;

    for (int k0 = 0; k0 < KTP; k0 += 32) {
        __syncthreads();
#pragma unroll
        for (int r = 0; r < 2; r++) {
            GLOAD_LDS16(pA[r] + k0, lA + r * 4096);
            GLOAD_LDS16(pB[r] + k0, lB + r * 4096);
        }
        __syncthreads();

        bf16x8 af[4], bf[4];
#pragma unroll
        for (int i = 0; i < 4; i++) {
            af[i] = *(const bf16x8*)&As[(wr * 64 + i * 16 + r16) * 32 + ((quad ^ aswz) * 8)];
            bf[i] = *(const bf16x8*)&Bs[(wc * 64 + i * 16 + r16) * 32 + ((quad ^ aswz) * 8)];
        }
#pragma unroll
        for (int i = 0; i < 4; i++)
#pragma unroll
            for (int j = 0; j < 4; j++)
                acc[i][j] = __builtin_amdgcn_mfma_f32_16x16x32_bf16(af[i], bf[j], acc[i][j], 0, 0, 0);
    }

#pragma unroll
    for (int i = 0; i < 4; i++) {
        int gm0 = m0 + wr * 64 + i * 16 + quad * 4;
#pragma unroll
        for (int reg = 0; reg < 4; reg++) {
            int m = gm0 + reg;
            float w = sim[(size_t)m * DP1 + D_];
#pragma unroll
            for (int j = 0; j < 4; j++) {
                int gn = n0 + wc * 64 + j * 16 + r16;
                out[(size_t)m * H_ + gn] = acc[i][j][reg] + w * desc[(size_t)m * H_ + gn];
            }
        }
    }
}

// ---------- fallback (ws too small): exact fp32, slow but correct ----------
__global__ __launch_bounds__(256)
void naive_logits_k(const float* __restrict__ vocab, const float* __restrict__ desc,
                    const float* __restrict__ defe, float* __restrict__ sim) {
    int d = blockIdx.x * 256 + threadIdx.x;
    if (d >= DP1) return;
    const float* vr = (d < D_) ? (vocab + (size_t)d * H_) : defe;
    const float* dr = desc + (size_t)blockIdx.y * H_;
    float s = 0.f;
    for (int h = 0; h < H_; h++) s = fmaf(dr[h], vr[h], s);
    sim[(size_t)blockIdx.y * DP1 + d] = s;
}

__global__ __launch_bounds__(256)
void naive_out_k(const float* __restrict__ vocab, const float* __restrict__ desc,
                 const float* __restrict__ sim, float* __restrict__ out) {
    int h = blockIdx.x * 256 + threadIdx.x;
    int bl = blockIdx.y;
    const float* sr = sim + (size_t)bl * DP1;
    float s = 0.f;
    for (int d = 0; d < D_; d++) s = fmaf(sr[d], vocab[(size_t)d * H_ + h], s);
    s += sr[D_] * desc[(size_t)bl * H_ + h];
    out[(size_t)bl * H_ + h] = s;
}

extern "C" void kernel_launch(void* const* d_in, const int* in_sizes, int n_in,
                              void* d_out, int out_size, void* d_ws, size_t ws_size,
                              hipStream_t stream) {
    (void)in_sizes; (void)n_in; (void)out_size;
    const float* vocab = (const float*)d_in[0];
    const float* desc  = (const float*)d_in[1];
    const float* defe  = (const float*)d_in[2];
    float* out = (float*)d_out;                          // concept: [4096][1024]
    float* sim = out + (size_t)BL * H_;                  // sim:     [4096][10001]

    // Phase-1 ws layout (bytes):
    //   desc_hi @ 0          (8,388,608)
    //   desc_lo @ 8,388,608  (8,388,608)
    //   fv_hi   @ 16,777,216 (20,971,520 = NPAD2*H_*2)
    //   fv_lo   @ 37,748,736 (20,971,520)          -> REQ1 = 58,720,256
    // Phase-2 (after gemm1, phase-1 arrays dead):
    //   vocab_t @ 0          (20,512,768 = H_*KTP*2)
    //   simb    @ 20,512,768 (82,051,072 = BL*KTP*2) -> REQ2 = 102,563,840
    //   P       @ 102,563,840 (67,108,864 = 4*BL*H_*4) -> REQ3 = 169,672,704
    const size_t REQ1 = 58720256ull;
    const size_t REQ2 = 102563840ull;
    const size_t REQ3 = 169672704ull;
    char* ws = (char*)d_ws;

    if (ws_size >= REQ2) {
        u16* dhi  = (u16*)(ws + 0);
        u16* dlo  = (u16*)(ws + 8388608);
        u16* fhi  = (u16*)(ws + 16777216);
        u16* flo  = (u16*)(ws + 37748736);
        u16* vt   = (u16*)(ws + 0);
        u16* simb = (u16*)(ws + 20512768);

        split_desc_k<<<16384, 256, 0, stream>>>(desc, dhi, dlo);
        split_fv_k<<<40960, 256, 0, stream>>>(vocab, defe, fhi, flo);
        gemm1_k<<<dim3(40, 32), 512, 0, stream>>>(dhi, dlo, fhi, flo, sim);
        softmax_k<<<4096, 256, 0, stream>>>(sim, simb);
        transpose_k<<<dim3(313, 32), 256, 0, stream>>>(vocab, vt);
        if (ws_size >= REQ3) {
            float* P = (float*)(ws + 102563840);
            gemm2_splitk_k<<<dim3(4, 32, 4), 512, 0, stream>>>(simb, vt, P);
            reduce_out_k<<<4096, 256, 0, stream>>>(P, sim, desc, out);
        } else {
            gemm2_big_k<<<dim3(8, 32), 256, 0, stream>>>(simb, vt, sim, desc, out);
        }
    } else if (ws_size >= REQ1) {
        u16* dhi = (u16*)(ws + 0);
        u16* dlo = (u16*)(ws + 8388608);
        u16* fhi = (u16*)(ws + 16777216);
        u16* flo = (u16*)(ws + 37748736);

        split_desc_k<<<16384, 256, 0, stream>>>(desc, dhi, dlo);
        split_fv_k<<<40960, 256, 0, stream>>>(vocab, defe, fhi, flo);
        gemm1_k<<<dim3(40, 32), 512, 0, stream>>>(dhi, dlo, fhi, flo, sim);
        softmax_k<<<4096, 256, 0, stream>>>(sim, (u16*)nullptr);
        naive_out_k<<<dim3(4, BL), 256, 0, stream>>>(vocab, desc, sim, out);
    } else {
        naive_logits_k<<<dim3(40, BL), 256, 0, stream>>>(vocab, desc, defe, sim);
        softmax_k<<<4096, 256, 0, stream>>>(sim, (u16*)nullptr);
        naive_out_k<<<dim3(4, BL), 256, 0, stream>>>(vocab, desc, sim, out);
    }
}